// Round 6
// baseline (310.190 us; speedup 1.0000x reference)
//
#include <hip/hip_runtime.h>
#include <hip/hip_bf16.h>
#include <math.h>

typedef unsigned short u16;
typedef unsigned int   u32;
typedef __attribute__((ext_vector_type(8))) short short8;   // 8 bf16
typedef __attribute__((ext_vector_type(4))) float f32x4;    // MFMA acc

// Problem constants
constexpr int G  = 8;
constexpr int D  = 128;
constexpr int H  = 256;
constexpr int DM = 1024;
constexpr int PK = 1024;
constexpr int NTOK = 8 * 2048;   // 16384

// ---------- scalar helpers ----------
__device__ __forceinline__ float bf2f(u16 u) {
    union { u32 i; float f; } v; v.i = ((u32)u) << 16; return v.f;
}
__device__ __forceinline__ u16 f2bf(float f) {
    union { float f; u32 i; } v; v.f = f;
    u32 x = v.i;
    return (u16)((x + 0x7fffu + ((x >> 16) & 1u)) >> 16);  // RNE
}
// packed f32x2 -> bf16x2 (RNE), single VALU op
__device__ __forceinline__ u32 pk_bf16(float lo, float hi) {
    u32 d;
    asm("v_cvt_pk_bf16_f32 %0, %1, %2" : "=v"(d) : "v"(lo), "v"(hi));
    return d;
}
__device__ __forceinline__ float f4c(const float4 v, int j) {
    return j == 0 ? v.x : j == 1 ? v.y : j == 2 ? v.z : v.w;
}
template <bool ISBF>
__device__ __forceinline__ float ld1(const void* p, size_t i) {
    if (ISBF) return bf2f(((const u16*)p)[i]);
    else      return ((const float*)p)[i];
}
template <bool ISBF>
__device__ __forceinline__ float4 ld4(const void* p, size_t i) {  // i % 4 == 0
    if (ISBF) {
        ushort4 v = *(const ushort4*)((const u16*)p + i);
        return make_float4(bf2f(v.x), bf2f(v.y), bf2f(v.z), bf2f(v.w));
    } else {
        return *(const float4*)((const float*)p + i);
    }
}
template <bool ISBF>
__device__ __forceinline__ void st4(void* p, size_t i, float4 v) {
    if (ISBF) {
        ushort4 o; o.x = f2bf(v.x); o.y = f2bf(v.y); o.z = f2bf(v.z); o.w = f2bf(v.w);
        *(ushort4*)((u16*)p + i) = o;
    } else {
        *(float4*)((float*)p + i) = v;
    }
}
// tanh-form GELU (max dev vs exact erf-GELU ~3e-4, tolerance 6.4e-2)
__device__ __forceinline__ float gelu_f(float v) {
    float u = v * (0.7978845608028654f + 0.0356774081f * v * v);
    float e = __expf(2.f * u);
    float th = 1.f - 2.f / (e + 1.f);
    return 0.5f * v * (1.f + th);
}
// async global->LDS, 16B per lane; LDS dest = wave-uniform base + lane*16
__device__ __forceinline__ void gload_lds16(const void* gp, void* lp) {
    __builtin_amdgcn_global_load_lds(
        (const __attribute__((address_space(1))) void*)gp,
        (__attribute__((address_space(3))) void*)lp, 16, 0, 0);
}

// ---------- dtype detect (proven R2) ----------
__global__ void detect_dtype(const void* xraw, int* flag) {
    __shared__ int cnt[256];
    const u32* xw = (const u32*)xraw;
    int tid = threadIdx.x, c = 0;
#pragma unroll
    for (int k = 0; k < 4; ++k) {
        u32 w = xw[tid * 4 + k];
#pragma unroll
        for (int h = 0; h < 2; ++h) {
            u16 u = (u16)(w >> (16 * h));
            int e = (u >> 7) & 0xFF;
            if ((u & 0x7FFF) == 0 || (e >= 112 && e <= 143)) ++c;
        }
    }
    cnt[tid] = c;
    __syncthreads();
    for (int s = 128; s > 0; s >>= 1) {
        if (tid < s) cnt[tid] += cnt[tid + s];
        __syncthreads();
    }
    if (tid == 0) flag[0] = (cnt[0] >= 1900) ? 1 : 0;
}

// ---------- MFMA-path weight prep ----------
// blocks [0,256): Wm -> wmt (WmT, bf16) via LDS 64x64 tile transpose
// blocks [256,640): fragment-major conv weights + gws.
//   w1p[((ktap*4+kk)*256 + h)*32 + j]  = w1[h][kk*32+j][ktap]   (j in [0,32))
//   w2p[((ktap*8+kk)*128 + d)*32 + j]  = w2[d][kk*32+j][ktap]
template <bool ISBF>
__global__ __launch_bounds__(256)
void prep_mfma(const void* __restrict__ w1, const void* __restrict__ w2,
               const void* __restrict__ Wm, const void* __restrict__ slot_gate,
               u16* __restrict__ w1p, u16* __restrict__ w2p,
               u16* __restrict__ wmt, float* __restrict__ gws,
               const int* __restrict__ flag) {
    if ((flag[0] != 0) != ISBF) return;
    __shared__ u16 tile[64][72];
    const int tid = threadIdx.x;
    if (blockIdx.x < 256) {
        const int kk0 = (blockIdx.x >> 4) * 64, n0 = (blockIdx.x & 15) * 64;
        const int r = tid >> 2, q = tid & 3;
#pragma unroll
        for (int j4 = 0; j4 < 4; ++j4) {
            float4 v = ld4<ISBF>(Wm, (size_t)(kk0 + r) * DM + n0 + q * 16 + j4 * 4);
            tile[r][q * 16 + j4 * 4 + 0] = f2bf(v.x);
            tile[r][q * 16 + j4 * 4 + 1] = f2bf(v.y);
            tile[r][q * 16 + j4 * 4 + 2] = f2bf(v.z);
            tile[r][q * 16 + j4 * 4 + 3] = f2bf(v.w);
        }
        __syncthreads();
        u16 op[16];
#pragma unroll
        for (int j = 0; j < 16; ++j) op[j] = tile[q * 16 + j][r];
        u16* dst = wmt + (size_t)(n0 + r) * DM + kk0 + q * 16;
        *(short8*)dst       = *(const short8*)&op[0];
        *(short8*)(dst + 8) = *(const short8*)&op[8];
        return;
    }
    int idx = (blockIdx.x - 256) * 256 + tid;
    if (idx < 3 * 4 * H * 32) {          // 98304 for each of w1p/w2p
        int jq = idx & 31;
        int t2 = idx >> 5;
        // w1p: t2 = (ktap*4+kk)*256 + h
        int h  = t2 & (H - 1);
        int ik = t2 >> 8;                // 0..11
        int kt1 = ik >> 2, kk1 = ik & 3;
        int dd = kk1 * 32 + jq;
        w1p[idx] = f2bf(ld1<ISBF>(w1, (size_t)(h * D + dd) * 3 + kt1));
        // w2p: t2 = (ktap*8+kk)*128 + d
        int d   = t2 & (D - 1);
        int ik2 = t2 >> 7;               // 0..23
        int kt2 = ik2 >> 3, kk2 = ik2 & 7;
        int hh = kk2 * 32 + jq;
        w2p[idx] = f2bf(ld1<ISBF>(w2, (size_t)(d * H + hh) * 3 + kt2));
    }
    if (idx < PK) gws[idx] = 2.f / (1.f + __expf(-ld1<ISBF>(slot_gate, idx)));
}

// ---------- fused gate+LN1+conv1+GELU+conv2+LN2 -> z (bf16) ----------
// 8 tokens/block, 256 threads (4 waves), 16x16x32 bf16 MFMA.
// conv1 split into two nt-passes (32-AGPR live acc) -> small reg footprint.
// R6: launch_bounds (256,4). LDS 38400B -> 160/38.4 = 4 blocks/CU; R5 showed
// VGPR=80(+32 AGPR) ~= 112 <= 128-reg cap, so 4 blocks should fit spill-free.
// (R2's (256,4) spill was with 64-wide acc1 + reg dbuf — both gone.)
// LDS union uni[74*256 u16] (37888 B):
//   xnpad  rows 0..72  : u16 base r*128            (u16 idx 0..9343)
//   midpad rows 0..36  : u16 base r*256            [M_lo]
//   midpad rows 37..72 : u16 base r*256+256        [M_hi, idx 9728..18943]
template <bool ISBF>
__global__ __launch_bounds__(256, 4)
void conv_fused(const void* __restrict__ x,
                const void* __restrict__ slot_bias,
                const void* __restrict__ pre_g,
                const void* __restrict__ pre_b,
                const void* __restrict__ b1,
                const void* __restrict__ b2,
                const void* __restrict__ pack_g,
                const void* __restrict__ pack_b,
                const u16* __restrict__ w1p,
                const u16* __restrict__ w2p,
                const float* __restrict__ gws,
                u16* __restrict__ zout,
                const int* __restrict__ flag) {
    if ((flag[0] != 0) != ISBF) return;

    __shared__ u16 uni[74 * 256];          // 37888 B union
    __shared__ float red_s[8][4], red_ss[8][4];

    const int tid  = threadIdx.x;
    const int lane = tid & 63, w = tid >> 6;
    const int quad = lane >> 4, col = lane & 15;
    const size_t tok0 = (size_t)blockIdx.x * 8;

    // ---- stage 0: zero xnpad halo rows (9 x 128) + M_hi halo rows {45,54,63,72} ----
    if (tid < 72) {
        int li = tid * 16, hr = li >> 7, e = li & 127;   // 8 threads/row, 16 u16 each
        u16* p = &uni[hr * 9 * 128 + e];
#pragma unroll
        for (int q = 0; q < 4; ++q) *(ushort4*)(p + 4 * q) = make_ushort4(0, 0, 0, 0);
    } else if (tid >= 128) {
        int li = (tid - 128) * 8, hr = li >> 8, e = li & 255;  // 32 threads/row, 8 u16
        int row = 45 + hr * 9;                       // 45,54,63,72
        u16* p = &uni[row * 256 + 256 + e];          // M_hi mapping
        *(ushort4*)p       = make_ushort4(0, 0, 0, 0);
        *(ushort4*)(p + 4) = make_ushort4(0, 0, 0, 0);
    }

    // per-thread slice for stage 1
    const int e0 = 4 * tid;
    const int d0 = e0 & (D - 1);
    const int g0 = tid >> 5;
    float gf[4], bff[4], pgf[4], pbf[4];
    {
        float4 gg  = *(const float4*)(gws + e0);        // precomputed 2*sigmoid, f32
        float4 sb4 = ld4<ISBF>(slot_bias, e0);
        float4 pg4 = ld4<ISBF>(pre_g, d0);
        float4 pb4 = ld4<ISBF>(pre_b, d0);
#pragma unroll
        for (int j = 0; j < 4; ++j) {
            gf[j]  = f4c(gg, j);
            bff[j] = f4c(sb4, j);
            pgf[j] = f4c(pg4, j);
            pbf[j] = f4c(pb4, j);
        }
    }

    // ---- stage 1: gate+bias, LN1, write xn (bf16, swizzled) ----
#pragma unroll
    for (int t = 0; t < 8; ++t) {
        float4 x4 = ld4<ISBF>(x, (tok0 + t) * PK + e0);
        float v[4];
#pragma unroll
        for (int j = 0; j < 4; ++j) v[j] = f4c(x4, j) * gf[j] + bff[j];
        float s = v[0] + v[1] + v[2] + v[3];
        float ss = v[0]*v[0] + v[1]*v[1] + v[2]*v[2] + v[3]*v[3];
#pragma unroll
        for (int m = 1; m < 32; m <<= 1) {
            s  += __shfl_xor(s,  m);
            ss += __shfl_xor(ss, m);
        }
        float mean = s * (1.f / 128.f);
        float var  = ss * (1.f / 128.f) - mean * mean;
        float rstd = rsqrtf(var + 1e-5f);
        uint2 o;
        o.x = pk_bf16((v[0] - mean) * rstd * pgf[0] + pbf[0],
                      (v[1] - mean) * rstd * pgf[1] + pbf[1]);
        o.y = pk_bf16((v[2] - mean) * rstd * pgf[2] + pbf[2],
                      (v[3] - mean) * rstd * pgf[3] + pbf[3]);
        int row  = t * 9 + g0 + 1;
        int addr = row * 128 + (((d0 >> 3) ^ (row & 7)) << 3) + (d0 & 7);
        *(uint2*)&uni[addr] = o;
    }
    __syncthreads();

    // per-lane (t,g) base rows for the 4 N-tiles (shared by conv1/conv2)
    int rowb[4];
#pragma unroll
    for (int nt = 0; nt < 4; ++nt) {
        int n = nt * 16 + col;
        rowb[nt] = (n >> 3) * 9 + (n & 7);   // row for tap0; +ktap walks g-1,g,g+1
    }
    const int alane1 = (w * 64 + col) * 32 + quad * 8;   // conv1 per-lane weight off
    const int alane2 = (w * 32 + col) * 32 + quad * 8;   // conv2

    // ---- stage 2: conv1 via MFMA, two nt-passes (32-AGPR live acc each) ----
#pragma unroll
    for (int pass = 0; pass < 2; ++pass) {
        const int ntb = (pass == 0) ? 2 : 0;     // pass0: t4..7, pass1: t0..3
        f32x4 acc[4][2] = {};                     // [mtl][ntl]
#pragma unroll
        for (int it = 0; it < 12; ++it) {
            const int ktap = it >> 2, kk = it & 3;
            short8 afr[4];
#pragma unroll
            for (int mtl = 0; mtl < 4; ++mtl)
                afr[mtl] = *(const short8*)(w1p + it * 8192 + mtl * 512 + alane1);
            short8 bfr[2];
#pragma unroll
            for (int ntl = 0; ntl < 2; ++ntl) {
                int rr = rowb[ntb + ntl] + ktap;
                int a  = rr * 128 + (((kk * 4 + quad) ^ (rr & 7)) << 3);
                bfr[ntl] = *(const short8*)&uni[a];
            }
#pragma unroll
            for (int mtl = 0; mtl < 4; ++mtl)
#pragma unroll
                for (int ntl = 0; ntl < 2; ++ntl)
                    acc[mtl][ntl] = __builtin_amdgcn_mfma_f32_16x16x32_bf16(
                        afr[mtl], bfr[ntl], acc[mtl][ntl], 0, 0, 0);
        }
        if (pass == 1) {
            // all waves done reading xnpad -> safe to overlay M_lo
            __syncthreads();
            // zero M_lo halo rows {0,9,18,27,36}
            if (tid < 160) {
                int li = tid * 8, hr = li >> 8, e = li & 255;
                u16* p = &uni[hr * 9 * 256 + e];   // rows {0,9,18,27,36}, M_lo map
                *(ushort4*)p       = make_ushort4(0, 0, 0, 0);
                *(ushort4*)(p + 4) = make_ushort4(0, 0, 0, 0);
            }
        }
        // epilogue: bias + GELU -> midpad (swizzled); pass0 rows>=37 (M_hi)
#pragma unroll
        for (int mtl = 0; mtl < 4; ++mtl) {
            int hq = w * 64 + mtl * 16 + quad * 4;
            float4 b1q = ld4<ISBF>(b1, hq);
#pragma unroll
            for (int ntl = 0; ntl < 2; ++ntl) {
                int row = rowb[ntb + ntl] + 1;
                uint2 o;
                o.x = pk_bf16(gelu_f(acc[mtl][ntl][0] + b1q.x),
                              gelu_f(acc[mtl][ntl][1] + b1q.y));
                o.y = pk_bf16(gelu_f(acc[mtl][ntl][2] + b1q.z),
                              gelu_f(acc[mtl][ntl][3] + b1q.w));
                int mb = row * 256 + ((row >= 37) ? 256 : 0);
                int a  = mb + (((hq >> 3) ^ (row & 7)) << 3) + (hq & 7);
                *(uint2*)&uni[a] = o;
            }
        }
    }
    __syncthreads();

    // ---- stage 3: conv2 via MFMA (C[d][(t,g)]) + bias + residual + LN2 + pack ----
    f32x4 acc2[2][4] = {};   // [mtl][nt]
#pragma unroll
    for (int it = 0; it < 24; ++it) {
        const int ktap = it >> 3, kk = it & 7;
        short8 cfr[2];
#pragma unroll
        for (int mtl = 0; mtl < 2; ++mtl)
            cfr[mtl] = *(const short8*)(w2p + it * 4096 + mtl * 512 + alane2);
        short8 bfr[4];
#pragma unroll
        for (int nt = 0; nt < 4; ++nt) {
            int rr = rowb[nt] + ktap;
            int mb = rr * 256 + ((rr >= 37) ? 256 : 0);
            int a  = mb + (((kk * 4 + quad) ^ (rr & 7)) << 3);
            bfr[nt] = *(const short8*)&uni[a];
        }
#pragma unroll
        for (int mtl = 0; mtl < 2; ++mtl)
#pragma unroll
            for (int nt = 0; nt < 4; ++nt)
                acc2[mtl][nt] = __builtin_amdgcn_mfma_f32_16x16x32_bf16(
                    cfr[mtl], bfr[nt], acc2[mtl][nt], 0, 0, 0);
    }
    // epilogue: val = conv2 + b2 + resid(x*gate+bias); LN2 over 1024/token
    {
        float vals[2][4][4];
        float s[4] = {0.f, 0.f, 0.f, 0.f}, ss[4] = {0.f, 0.f, 0.f, 0.f};
#pragma unroll
        for (int mtl = 0; mtl < 2; ++mtl) {
            int dq = w * 32 + mtl * 16 + quad * 4;
            float4 b2q = ld4<ISBF>(b2, dq);
#pragma unroll
            for (int nt = 0; nt < 4; ++nt) {
                int n = nt * 16 + col; int t = n >> 3, g = n & 7;
                int e = g * D + dq;
                float4 xr = ld4<ISBF>(x, (tok0 + t) * PK + e);
                float4 gq = *(const float4*)(gws + e);
                float4 bq = ld4<ISBF>(slot_bias, e);
#pragma unroll
                for (int r = 0; r < 4; ++r) {
                    float resid = f4c(xr, r) * f4c(gq, r) + f4c(bq, r);
                    float val = acc2[mtl][nt][r] + f4c(b2q, r) + resid;
                    vals[mtl][nt][r] = val;
                    s[nt] += val; ss[nt] += val * val;
                }
            }
        }
        // reduce over lanes sharing token t: masks {1,2,4,16,32}
#pragma unroll
        for (int nt = 0; nt < 4; ++nt) {
            s[nt] += __shfl_xor(s[nt], 1);  ss[nt] += __shfl_xor(ss[nt], 1);
            s[nt] += __shfl_xor(s[nt], 2);  ss[nt] += __shfl_xor(ss[nt], 2);
            s[nt] += __shfl_xor(s[nt], 4);  ss[nt] += __shfl_xor(ss[nt], 4);
            s[nt] += __shfl_xor(s[nt], 16); ss[nt] += __shfl_xor(ss[nt], 16);
            s[nt] += __shfl_xor(s[nt], 32); ss[nt] += __shfl_xor(ss[nt], 32);
        }
        if (quad == 0 && (col & 7) == 0) {
#pragma unroll
            for (int nt = 0; nt < 4; ++nt) {
                int t = 2 * nt + (col >> 3);
                red_s[t][w] = s[nt]; red_ss[t][w] = ss[nt];
            }
        }
        __syncthreads();
        float mean[4], rstd[4];
#pragma unroll
        for (int nt = 0; nt < 4; ++nt) {
            int t = 2 * nt + (col >> 3);
            float st  = red_s[t][0] + red_s[t][1] + red_s[t][2] + red_s[t][3];
            float sst = red_ss[t][0] + red_ss[t][1] + red_ss[t][2] + red_ss[t][3];
            mean[nt] = st * (1.f / 1024.f);
            float var = sst * (1.f / 1024.f) - mean[nt] * mean[nt];
            rstd[nt] = rsqrtf(var + 1e-5f);
        }
#pragma unroll
        for (int mtl = 0; mtl < 2; ++mtl) {
            int dq = w * 32 + mtl * 16 + quad * 4;
#pragma unroll
            for (int nt = 0; nt < 4; ++nt) {
                int n = nt * 16 + col; int t = n >> 3, g = n & 7;
                int e = g * D + dq;
                float4 pg4 = ld4<ISBF>(pack_g, e);
                float4 pb4 = ld4<ISBF>(pack_b, e);
                float zv[4];
#pragma unroll
                for (int r = 0; r < 4; ++r)
                    zv[r] = (vals[mtl][nt][r] - mean[nt]) * rstd[nt] * f4c(pg4, r)
                            + f4c(pb4, r);
                uint2 o;
                o.x = pk_bf16(zv[0], zv[1]);
                o.y = pk_bf16(zv[2], zv[3]);
                *(uint2*)(zout + (tok0 + t) * PK + e) = o;
            }
        }
    }
}

// ---------- z @ Wm + bm via MFMA, m97 structure + 2-phase LDS double-buffer ----------
// stage(next) issued BEFORE compute(cur); single barrier per K-step (T3-minimum).
template <bool ISBF>
__global__ __launch_bounds__(256, 2)
void gemm_out(const u16* __restrict__ z, const u16* __restrict__ wmt,
              const void* __restrict__ bm, void* __restrict__ out,
              const int* __restrict__ flag) {
    if ((flag[0] != 0) != ISBF) return;
    __shared__ u16 As[2][128 * 32];   // z tile   [m][k] linear (gload_lds order)
    __shared__ u16 Bs[2][128 * 32];   // WmT tile [n][k] linear
    const int tid = threadIdx.x, lane = tid & 63, w = tid >> 6;
    const int quad = lane >> 4, col = lane & 15;
    // XCD-bijective swizzle (nwg = 1024, % 8 == 0)
    const int swz = ((blockIdx.x & 7) << 7) | ((int)blockIdx.x >> 3);
    const int bm0 = (swz >> 3) * 128, bn0 = (swz & 7) * 128;
    const int wm = w >> 1, wn = w & 1;
    const int c0 = w * 128 + lane;   // staging chunk base for this lane
    f32x4 acc[4][4] = {};            // [nt][mt]

    const u16* zrow0 = z   + (size_t)bm0 * DM;
    const u16* wrow0 = wmt + (size_t)bn0 * DM;

    auto stage = [&](int buf, int k0) {
#pragma unroll
        for (int q = 0; q < 2; ++q) {
            int c = c0 + q * 64;
            int r = c >> 2, kc = (c & 3) * 8;
            gload_lds16(zrow0 + (size_t)r * DM + k0 + kc, &As[buf][(w * 2 + q) * 512]);
            gload_lds16(wrow0 + (size_t)r * DM + k0 + kc, &Bs[buf][(w * 2 + q) * 512]);
        }
    };

    stage(0, 0);
    __syncthreads();
#pragma unroll 2
    for (int t = 0; t < 32; ++t) {
        const int cur = t & 1;
        if (t < 31) stage(cur ^ 1, (t + 1) * 32);    // prefetch overlaps compute
        short8 zfr[4], wfr[4];
#pragma unroll
        for (int mt = 0; mt < 4; ++mt)
            zfr[mt] = *(const short8*)&As[cur][(wm * 64 + mt * 16 + col) * 32 + quad * 8];
#pragma unroll
        for (int nt = 0; nt < 4; ++nt)
            wfr[nt] = *(const short8*)&Bs[cur][(wn * 64 + nt * 16 + col) * 32 + quad * 8];
#pragma unroll
        for (int nt = 0; nt < 4; ++nt)
#pragma unroll
            for (int mt = 0; mt < 4; ++mt)
                acc[nt][mt] = __builtin_amdgcn_mfma_f32_16x16x32_bf16(
                    wfr[nt], zfr[mt], acc[nt][mt], 0, 0, 0);
        __syncthreads();   // drains this wave's prefetch + guards cur-buf reuse
    }
    // epilogue: C rows = n (quad*4+r), cols = m
#pragma unroll
    for (int nt = 0; nt < 4; ++nt) {
        int n = bn0 + wn * 64 + nt * 16 + quad * 4;
        float4 bq = ld4<ISBF>(bm, n);
#pragma unroll
        for (int mt = 0; mt < 4; ++mt) {
            int m = bm0 + wm * 64 + mt * 16 + col;
            float4 o = make_float4(acc[nt][mt][0] + bq.x, acc[nt][mt][1] + bq.y,
                                   acc[nt][mt][2] + bq.z, acc[nt][mt][3] + bq.w);
            st4<ISBF>(out, (size_t)m * DM + n, o);
        }
    }
}

// ---------- scalar fallback (R2-proven), raw weights ----------
template <bool ISBF>
__global__ __launch_bounds__(256)
void slotconv_scalar(const void* __restrict__ x,
                     const void* __restrict__ slot_gate,
                     const void* __restrict__ slot_bias,
                     const void* __restrict__ pre_g,
                     const void* __restrict__ pre_b,
                     const void* __restrict__ w1raw,
                     const void* __restrict__ b1,
                     const void* __restrict__ w2raw,
                     const void* __restrict__ b2,
                     const void* __restrict__ pack_g,
                     const void* __restrict__ pack_b,
                     const void* __restrict__ Wm,
                     const void* __restrict__ bm,
                     void* __restrict__ out,
                     const int* __restrict__ flag) {
    if ((flag[0] != 0) != ISBF) return;
    __shared__ float resid[G * D];
    __shared__ float xnpadf[(G + 2) * D];
    __shared__ float midpadf[(G + 2) * H];
    __shared__ float zbuf[4][PK];
    __shared__ float red[8];
    const int tid = threadIdx.x;
    if (tid < D) { xnpadf[tid] = 0.f; xnpadf[(G + 1) * D + tid] = 0.f; }
    midpadf[tid] = 0.f; midpadf[(G + 1) * H + tid] = 0.f;
    const int e0 = 4 * tid;
    const int d0 = e0 & (D - 1);
    const int g0 = tid >> 5;
    float gate[4], bias[4], pgf[4], pbf[4];
    {
        float4 sg4 = ld4<ISBF>(slot_gate, e0);
        float4 sb4 = ld4<ISBF>(slot_bias, e0);
        float4 pg4 = ld4<ISBF>(pre_g, d0);
        float4 pb4 = ld4<ISBF>(pre_b, d0);
#pragma unroll
        for (int j = 0; j < 4; ++j) {
            gate[j] = 2.f / (1.f + __expf(-f4c(sg4, j)));
            bias[j] = f4c(sb4, j);
            pgf[j] = f4c(pg4, j); pbf[j] = f4c(pb4, j);
        }
    }
    for (int t = 0; t < 4; ++t) {
        __syncthreads();
        const size_t tok = (size_t)blockIdx.x * 4 + t;
        {
            float4 x4 = ld4<ISBF>(x, tok * PK + e0);
            float v[4];
#pragma unroll
            for (int j = 0; j < 4; ++j) v[j] = f4c(x4, j) * gate[j] + bias[j];
            *(float4*)&resid[e0] = make_float4(v[0], v[1], v[2], v[3]);
            float s = v[0]+v[1]+v[2]+v[3], ss = v[0]*v[0]+v[1]*v[1]+v[2]*v[2]+v[3]*v[3];
#pragma unroll
            for (int m = 1; m < 32; m <<= 1) { s += __shfl_xor(s, m); ss += __shfl_xor(ss, m); }
            float mean = s * (1.f/128.f), var = ss * (1.f/128.f) - mean*mean;
            float rstd = rsqrtf(var + 1e-5f);
            float xn[4];
#pragma unroll
            for (int j = 0; j < 4; ++j) xn[j] = (v[j]-mean)*rstd*pgf[j]+pbf[j];
            *(float4*)&xnpadf[(g0+1)*D + d0] = make_float4(xn[0],xn[1],xn[2],xn[3]);
        }
        __syncthreads();
        {
            const int h = tid;
            float acc[G];
#pragma unroll
            for (int g = 0; g < G; ++g) acc[g] = 0.f;
            for (int d4 = 0; d4 < D; d4 += 4) {
                float4 xr4[G + 2];
#pragma unroll
                for (int r = 0; r < G + 2; ++r) xr4[r] = *(const float4*)&xnpadf[r * D + d4];
#pragma unroll
                for (int j = 0; j < 4; ++j) {
                    size_t o = (size_t)h * (D * 3) + (d4 + j) * 3;
                    float wk0 = ld1<ISBF>(w1raw, o), wk1 = ld1<ISBF>(w1raw, o+1), wk2 = ld1<ISBF>(w1raw, o+2);
#pragma unroll
                    for (int g = 0; g < G; ++g) {
                        acc[g] += f4c(xr4[g+0], j) * wk0;
                        acc[g] += f4c(xr4[g+1], j) * wk1;
                        acc[g] += f4c(xr4[g+2], j) * wk2;
                    }
                }
            }
            float b1h = ld1<ISBF>(b1, tid);
#pragma unroll
            for (int g = 0; g < G; ++g) {
                float m = acc[g] + b1h;
                midpadf[(g+1)*H + h] = 0.5f * m * (1.f + erff(m * 0.70710678118654752f));
            }
        }
        __syncthreads();
        {
            const int dd = tid & (D - 1);
            const int gh = tid >> 7;
            float acc2[4] = {0.f,0.f,0.f,0.f};
            for (int h4 = 0; h4 < H; h4 += 4) {
                float4 mr4[6];
#pragma unroll
                for (int r = 0; r < 6; ++r) mr4[r] = *(const float4*)&midpadf[(gh*4+r)*H + h4];
#pragma unroll
                for (int j = 0; j < 4; ++j) {
                    size_t o = (size_t)dd * (H * 3) + (h4 + j) * 3;
                    float wk0 = ld1<ISBF>(w2raw, o), wk1 = ld1<ISBF>(w2raw, o+1), wk2 = ld1<ISBF>(w2raw, o+2);
#pragma unroll
                    for (int jj = 0; jj < 4; ++jj) {
                        acc2[jj] += f4c(mr4[jj+0], j) * wk0;
                        acc2[jj] += f4c(mr4[jj+1], j) * wk1;
                        acc2[jj] += f4c(mr4[jj+2], j) * wk2;
                    }
                }
            }
            float b2d = ld1<ISBF>(b2, dd);
            float vz[4], s = 0.f, ss = 0.f;
#pragma unroll
            for (int j = 0; j < 4; ++j) {
                int e = (gh*4+j)*D + dd;
                float val = acc2[j] + b2d + resid[e];
                vz[j] = val; s += val; ss += val*val;
            }
#pragma unroll
            for (int m = 1; m < 64; m <<= 1) { s += __shfl_xor(s, m); ss += __shfl_xor(ss, m); }
            const int wid = tid >> 6;
            if ((tid & 63) == 0) { red[wid*2] = s; red[wid*2+1] = ss; }
            __syncthreads();
            float st = red[0]+red[2]+red[4]+red[6], sst = red[1]+red[3]+red[5]+red[7];
            float mean = st * (1.f/1024.f), var = sst * (1.f/1024.f) - mean*mean;
            float rstd = rsqrtf(var + 1e-5f);
#pragma unroll
            for (int j = 0; j < 4; ++j) {
                int e = (gh*4+j)*D + dd;
                zbuf[t][e] = (vz[j]-mean)*rstd*ld1<ISBF>(pack_g, e) + ld1<ISBF>(pack_b, e);
            }
        }
    }
    __syncthreads();
    {
        float accm[4][4];
#pragma unroll
        for (int t = 0; t < 4; ++t)
#pragma unroll
            for (int j = 0; j < 4; ++j) accm[t][j] = 0.f;
        for (int p4 = 0; p4 < PK; p4 += 4) {
            float4 z4[4];
#pragma unroll
            for (int t = 0; t < 4; ++t) z4[t] = *(const float4*)&zbuf[t][p4];
#pragma unroll
            for (int pp = 0; pp < 4; ++pp) {
                float4 w4 = ld4<ISBF>(Wm, (size_t)(p4 + pp) * DM + e0);
#pragma unroll
                for (int t = 0; t < 4; ++t) {
                    float zp = f4c(z4[t], pp);
                    accm[t][0] += zp * w4.x; accm[t][1] += zp * w4.y;
                    accm[t][2] += zp * w4.z; accm[t][3] += zp * w4.w;
                }
            }
        }
        float4 bm4 = ld4<ISBF>(bm, e0);
#pragma unroll
        for (int t = 0; t < 4; ++t) {
            const size_t tok = (size_t)blockIdx.x * 4 + t;
            st4<ISBF>(out, tok * DM + e0,
                      make_float4(accm[t][0]+bm4.x, accm[t][1]+bm4.y,
                                  accm[t][2]+bm4.z, accm[t][3]+bm4.w));
        }
    }
}

extern "C" void kernel_launch(void* const* d_in, const int* in_sizes, int n_in,
                              void* d_out, int out_size, void* d_ws, size_t ws_size,
                              hipStream_t stream) {
    const void* x   = d_in[0];
    const void* sg  = d_in[1];
    const void* sb  = d_in[2];
    const void* pg  = d_in[3];
    const void* pb  = d_in[4];
    const void* w1  = d_in[5];
    const void* b1  = d_in[6];
    const void* w2  = d_in[7];
    const void* b2  = d_in[8];
    const void* pkg = d_in[9];
    const void* pkb = d_in[10];
    const void* Wm  = d_in[11];
    const void* bm  = d_in[12];

    int* flag = (int*)d_ws;
    u16* base = (u16*)((char*)d_ws + 16);
    u16* w1p = base;                       // 98304 el
    u16* w2p = base + 98304;               // 98304 el
    u16* wmt = base + 196608;              // 1048576 el
    u16* zws = base + 196608 + 1048576;    // 16777216 el
    float* gws = (float*)(base + 18022400);          // 1024 f32
    const size_t ws_needed = 16 + (size_t)18022400 * sizeof(u16) + PK * sizeof(float);

    detect_dtype<<<1, 256, 0, stream>>>(x, flag);

    if (ws_size >= ws_needed) {
        prep_mfma<true ><<<640, 256, 0, stream>>>(w1, w2, Wm, sg, w1p, w2p, wmt, gws, flag);
        prep_mfma<false><<<640, 256, 0, stream>>>(w1, w2, Wm, sg, w1p, w2p, wmt, gws, flag);
        conv_fused<true ><<<NTOK / 8, 256, 0, stream>>>(x, sb, pg, pb, b1, b2, pkg, pkb, w1p, w2p, gws, zws, flag);
        conv_fused<false><<<NTOK / 8, 256, 0, stream>>>(x, sb, pg, pb, b1, b2, pkg, pkb, w1p, w2p, gws, zws, flag);
        gemm_out<true ><<<(NTOK / 128) * (DM / 128), 256, 0, stream>>>(zws, wmt, bm, d_out, flag);
        gemm_out<false><<<(NTOK / 128) * (DM / 128), 256, 0, stream>>>(zws, wmt, bm, d_out, flag);
    } else {
        slotconv_scalar<true ><<<NTOK / 4, 256, 0, stream>>>(
            x, sg, sb, pg, pb, w1, b1, w2, b2, pkg, pkb, Wm, bm, d_out, flag);
        slotconv_scalar<false><<<NTOK / 4, 256, 0, stream>>>(
            x, sg, sb, pg, pb, w1, b1, w2, b2, pkg, pkb, Wm, bm, d_out, flag);
    }
}

// Round 7
// 300.109 us; speedup vs baseline: 1.0336x; 1.0336x over previous
//
#include <hip/hip_runtime.h>
#include <hip/hip_bf16.h>
#include <math.h>

typedef unsigned short u16;
typedef unsigned int   u32;
typedef __attribute__((ext_vector_type(8))) short short8;   // 8 bf16
typedef __attribute__((ext_vector_type(4))) float f32x4;    // MFMA acc

// Problem constants
constexpr int G  = 8;
constexpr int D  = 128;
constexpr int H  = 256;
constexpr int DM = 1024;
constexpr int PK = 1024;
constexpr int NTOK = 8 * 2048;   // 16384

// ---------- scalar helpers ----------
__device__ __forceinline__ float bf2f(u16 u) {
    union { u32 i; float f; } v; v.i = ((u32)u) << 16; return v.f;
}
__device__ __forceinline__ u16 f2bf(float f) {
    union { float f; u32 i; } v; v.f = f;
    u32 x = v.i;
    return (u16)((x + 0x7fffu + ((x >> 16) & 1u)) >> 16);  // RNE
}
// packed f32x2 -> bf16x2 (RNE), single VALU op
__device__ __forceinline__ u32 pk_bf16(float lo, float hi) {
    u32 d;
    asm("v_cvt_pk_bf16_f32 %0, %1, %2" : "=v"(d) : "v"(lo), "v"(hi));
    return d;
}
__device__ __forceinline__ float f4c(const float4 v, int j) {
    return j == 0 ? v.x : j == 1 ? v.y : j == 2 ? v.z : v.w;
}
template <bool ISBF>
__device__ __forceinline__ float ld1(const void* p, size_t i) {
    if (ISBF) return bf2f(((const u16*)p)[i]);
    else      return ((const float*)p)[i];
}
template <bool ISBF>
__device__ __forceinline__ float4 ld4(const void* p, size_t i) {  // i % 4 == 0
    if (ISBF) {
        ushort4 v = *(const ushort4*)((const u16*)p + i);
        return make_float4(bf2f(v.x), bf2f(v.y), bf2f(v.z), bf2f(v.w));
    } else {
        return *(const float4*)((const float*)p + i);
    }
}
template <bool ISBF>
__device__ __forceinline__ void st4(void* p, size_t i, float4 v) {
    if (ISBF) {
        ushort4 o; o.x = f2bf(v.x); o.y = f2bf(v.y); o.z = f2bf(v.z); o.w = f2bf(v.w);
        *(ushort4*)((u16*)p + i) = o;
    } else {
        *(float4*)((float*)p + i) = v;
    }
}
// tanh-form GELU (max dev vs exact erf-GELU ~3e-4, tolerance 6.4e-2)
__device__ __forceinline__ float gelu_f(float v) {
    float u = v * (0.7978845608028654f + 0.0356774081f * v * v);
    float e = __expf(2.f * u);
    float th = 1.f - 2.f / (e + 1.f);
    return 0.5f * v * (1.f + th);
}
// async global->LDS, 16B per lane; LDS dest = wave-uniform base + lane*16
__device__ __forceinline__ void gload_lds16(const void* gp, void* lp) {
    __builtin_amdgcn_global_load_lds(
        (const __attribute__((address_space(1))) void*)gp,
        (__attribute__((address_space(3))) void*)lp, 16, 0, 0);
}

// ---------- dtype detect (proven R2) ----------
__global__ void detect_dtype(const void* xraw, int* flag) {
    __shared__ int cnt[256];
    const u32* xw = (const u32*)xraw;
    int tid = threadIdx.x, c = 0;
#pragma unroll
    for (int k = 0; k < 4; ++k) {
        u32 w = xw[tid * 4 + k];
#pragma unroll
        for (int h = 0; h < 2; ++h) {
            u16 u = (u16)(w >> (16 * h));
            int e = (u >> 7) & 0xFF;
            if ((u & 0x7FFF) == 0 || (e >= 112 && e <= 143)) ++c;
        }
    }
    cnt[tid] = c;
    __syncthreads();
    for (int s = 128; s > 0; s >>= 1) {
        if (tid < s) cnt[tid] += cnt[tid + s];
        __syncthreads();
    }
    if (tid == 0) flag[0] = (cnt[0] >= 1900) ? 1 : 0;
}

// ---------- MFMA-path weight prep ----------
// blocks [0,256): Wm -> wmt (WmT, bf16) via LDS 64x64 tile transpose
// blocks [256,640): fragment-major conv weights + gws.
//   w1p[((ktap*4+kk)*256 + h)*32 + j]  = w1[h][kk*32+j][ktap]   (j in [0,32))
//   w2p[((ktap*8+kk)*128 + d)*32 + j]  = w2[d][kk*32+j][ktap]
template <bool ISBF>
__global__ __launch_bounds__(256)
void prep_mfma(const void* __restrict__ w1, const void* __restrict__ w2,
               const void* __restrict__ Wm, const void* __restrict__ slot_gate,
               u16* __restrict__ w1p, u16* __restrict__ w2p,
               u16* __restrict__ wmt, float* __restrict__ gws,
               const int* __restrict__ flag) {
    if ((flag[0] != 0) != ISBF) return;
    __shared__ u16 tile[64][72];
    const int tid = threadIdx.x;
    if (blockIdx.x < 256) {
        const int kk0 = (blockIdx.x >> 4) * 64, n0 = (blockIdx.x & 15) * 64;
        const int r = tid >> 2, q = tid & 3;
#pragma unroll
        for (int j4 = 0; j4 < 4; ++j4) {
            float4 v = ld4<ISBF>(Wm, (size_t)(kk0 + r) * DM + n0 + q * 16 + j4 * 4);
            tile[r][q * 16 + j4 * 4 + 0] = f2bf(v.x);
            tile[r][q * 16 + j4 * 4 + 1] = f2bf(v.y);
            tile[r][q * 16 + j4 * 4 + 2] = f2bf(v.z);
            tile[r][q * 16 + j4 * 4 + 3] = f2bf(v.w);
        }
        __syncthreads();
        u16 op[16];
#pragma unroll
        for (int j = 0; j < 16; ++j) op[j] = tile[q * 16 + j][r];
        u16* dst = wmt + (size_t)(n0 + r) * DM + kk0 + q * 16;
        *(short8*)dst       = *(const short8*)&op[0];
        *(short8*)(dst + 8) = *(const short8*)&op[8];
        return;
    }
    int idx = (blockIdx.x - 256) * 256 + tid;
    if (idx < 3 * 4 * H * 32) {          // 98304 for each of w1p/w2p
        int jq = idx & 31;
        int t2 = idx >> 5;
        // w1p: t2 = (ktap*4+kk)*256 + h
        int h  = t2 & (H - 1);
        int ik = t2 >> 8;                // 0..11
        int kt1 = ik >> 2, kk1 = ik & 3;
        int dd = kk1 * 32 + jq;
        w1p[idx] = f2bf(ld1<ISBF>(w1, (size_t)(h * D + dd) * 3 + kt1));
        // w2p: t2 = (ktap*8+kk)*128 + d
        int d   = t2 & (D - 1);
        int ik2 = t2 >> 7;               // 0..23
        int kt2 = ik2 >> 3, kk2 = ik2 & 7;
        int hh = kk2 * 32 + jq;
        w2p[idx] = f2bf(ld1<ISBF>(w2, (size_t)(d * H + hh) * 3 + kt2));
    }
    if (idx < PK) gws[idx] = 2.f / (1.f + __expf(-ld1<ISBF>(slot_gate, idx)));
}

// ---------- fused gate+LN1+conv1+GELU+conv2+LN2 -> z (bf16) ----------
// 8 tokens/block, 256 threads (4 waves), 16x16x32 bf16 MFMA.
// conv1 split into two nt-passes (32-AGPR live acc) -> fits (256,3), no spill.
// PROVEN R5: (256,3) -> VGPR 80, WRITE 33MB (clean), 134 us. (256,4) spills
// (R6: 128-reg cap < ~140 footprint -> WRITE 78MB, 146 us). Do not raise.
// LDS union uni[74*256 u16] (37888 B):
//   xnpad  rows 0..72  : u16 base r*128            (u16 idx 0..9343)
//   midpad rows 0..36  : u16 base r*256            [M_lo]
//   midpad rows 37..72 : u16 base r*256+256        [M_hi, idx 9728..18943]
template <bool ISBF>
__global__ __launch_bounds__(256, 3)
void conv_fused(const void* __restrict__ x,
                const void* __restrict__ slot_bias,
                const void* __restrict__ pre_g,
                const void* __restrict__ pre_b,
                const void* __restrict__ b1,
                const void* __restrict__ b2,
                const void* __restrict__ pack_g,
                const void* __restrict__ pack_b,
                const u16* __restrict__ w1p,
                const u16* __restrict__ w2p,
                const float* __restrict__ gws,
                u16* __restrict__ zout,
                const int* __restrict__ flag) {
    if ((flag[0] != 0) != ISBF) return;

    __shared__ u16 uni[74 * 256];          // 37888 B union
    __shared__ float red_s[8][4], red_ss[8][4];

    const int tid  = threadIdx.x;
    const int lane = tid & 63, w = tid >> 6;
    const int quad = lane >> 4, col = lane & 15;
    const size_t tok0 = (size_t)blockIdx.x * 8;

    // ---- stage 0: zero xnpad halo rows (9 x 128) + M_hi halo rows {45,54,63,72} ----
    if (tid < 72) {
        int li = tid * 16, hr = li >> 7, e = li & 127;   // 8 threads/row, 16 u16 each
        u16* p = &uni[hr * 9 * 128 + e];
#pragma unroll
        for (int q = 0; q < 4; ++q) *(ushort4*)(p + 4 * q) = make_ushort4(0, 0, 0, 0);
    } else if (tid >= 128) {
        int li = (tid - 128) * 8, hr = li >> 8, e = li & 255;  // 32 threads/row, 8 u16
        int row = 45 + hr * 9;                       // 45,54,63,72
        u16* p = &uni[row * 256 + 256 + e];          // M_hi mapping
        *(ushort4*)p       = make_ushort4(0, 0, 0, 0);
        *(ushort4*)(p + 4) = make_ushort4(0, 0, 0, 0);
    }

    // per-thread slice for stage 1
    const int e0 = 4 * tid;
    const int d0 = e0 & (D - 1);
    const int g0 = tid >> 5;
    float gf[4], bff[4], pgf[4], pbf[4];
    {
        float4 gg  = *(const float4*)(gws + e0);        // precomputed 2*sigmoid, f32
        float4 sb4 = ld4<ISBF>(slot_bias, e0);
        float4 pg4 = ld4<ISBF>(pre_g, d0);
        float4 pb4 = ld4<ISBF>(pre_b, d0);
#pragma unroll
        for (int j = 0; j < 4; ++j) {
            gf[j]  = f4c(gg, j);
            bff[j] = f4c(sb4, j);
            pgf[j] = f4c(pg4, j);
            pbf[j] = f4c(pb4, j);
        }
    }

    // ---- stage 1: gate+bias, LN1, write xn (bf16, swizzled) ----
#pragma unroll
    for (int t = 0; t < 8; ++t) {
        float4 x4 = ld4<ISBF>(x, (tok0 + t) * PK + e0);
        float v[4];
#pragma unroll
        for (int j = 0; j < 4; ++j) v[j] = f4c(x4, j) * gf[j] + bff[j];
        float s = v[0] + v[1] + v[2] + v[3];
        float ss = v[0]*v[0] + v[1]*v[1] + v[2]*v[2] + v[3]*v[3];
#pragma unroll
        for (int m = 1; m < 32; m <<= 1) {
            s  += __shfl_xor(s,  m);
            ss += __shfl_xor(ss, m);
        }
        float mean = s * (1.f / 128.f);
        float var  = ss * (1.f / 128.f) - mean * mean;
        float rstd = rsqrtf(var + 1e-5f);
        uint2 o;
        o.x = pk_bf16((v[0] - mean) * rstd * pgf[0] + pbf[0],
                      (v[1] - mean) * rstd * pgf[1] + pbf[1]);
        o.y = pk_bf16((v[2] - mean) * rstd * pgf[2] + pbf[2],
                      (v[3] - mean) * rstd * pgf[3] + pbf[3]);
        int row  = t * 9 + g0 + 1;
        int addr = row * 128 + (((d0 >> 3) ^ (row & 7)) << 3) + (d0 & 7);
        *(uint2*)&uni[addr] = o;
    }
    __syncthreads();

    // per-lane (t,g) base rows for the 4 N-tiles (shared by conv1/conv2)
    int rowb[4];
#pragma unroll
    for (int nt = 0; nt < 4; ++nt) {
        int n = nt * 16 + col;
        rowb[nt] = (n >> 3) * 9 + (n & 7);   // row for tap0; +ktap walks g-1,g,g+1
    }
    const int alane1 = (w * 64 + col) * 32 + quad * 8;   // conv1 per-lane weight off
    const int alane2 = (w * 32 + col) * 32 + quad * 8;   // conv2

    // ---- stage 2: conv1 via MFMA, two nt-passes (32-AGPR live acc each) ----
#pragma unroll
    for (int pass = 0; pass < 2; ++pass) {
        const int ntb = (pass == 0) ? 2 : 0;     // pass0: t4..7, pass1: t0..3
        f32x4 acc[4][2] = {};                     // [mtl][ntl]
#pragma unroll
        for (int it = 0; it < 12; ++it) {
            const int ktap = it >> 2, kk = it & 3;
            short8 afr[4];
#pragma unroll
            for (int mtl = 0; mtl < 4; ++mtl)
                afr[mtl] = *(const short8*)(w1p + it * 8192 + mtl * 512 + alane1);
            short8 bfr[2];
#pragma unroll
            for (int ntl = 0; ntl < 2; ++ntl) {
                int rr = rowb[ntb + ntl] + ktap;
                int a  = rr * 128 + (((kk * 4 + quad) ^ (rr & 7)) << 3);
                bfr[ntl] = *(const short8*)&uni[a];
            }
#pragma unroll
            for (int mtl = 0; mtl < 4; ++mtl)
#pragma unroll
                for (int ntl = 0; ntl < 2; ++ntl)
                    acc[mtl][ntl] = __builtin_amdgcn_mfma_f32_16x16x32_bf16(
                        afr[mtl], bfr[ntl], acc[mtl][ntl], 0, 0, 0);
        }
        if (pass == 1) {
            // all waves done reading xnpad -> safe to overlay M_lo
            __syncthreads();
            // zero M_lo halo rows {0,9,18,27,36}
            if (tid < 160) {
                int li = tid * 8, hr = li >> 8, e = li & 255;
                u16* p = &uni[hr * 9 * 256 + e];   // rows {0,9,18,27,36}, M_lo map
                *(ushort4*)p       = make_ushort4(0, 0, 0, 0);
                *(ushort4*)(p + 4) = make_ushort4(0, 0, 0, 0);
            }
        }
        // epilogue: bias + GELU -> midpad (swizzled); pass0 rows>=37 (M_hi)
#pragma unroll
        for (int mtl = 0; mtl < 4; ++mtl) {
            int hq = w * 64 + mtl * 16 + quad * 4;
            float4 b1q = ld4<ISBF>(b1, hq);
#pragma unroll
            for (int ntl = 0; ntl < 2; ++ntl) {
                int row = rowb[ntb + ntl] + 1;
                uint2 o;
                o.x = pk_bf16(gelu_f(acc[mtl][ntl][0] + b1q.x),
                              gelu_f(acc[mtl][ntl][1] + b1q.y));
                o.y = pk_bf16(gelu_f(acc[mtl][ntl][2] + b1q.z),
                              gelu_f(acc[mtl][ntl][3] + b1q.w));
                int mb = row * 256 + ((row >= 37) ? 256 : 0);
                int a  = mb + (((hq >> 3) ^ (row & 7)) << 3) + (hq & 7);
                *(uint2*)&uni[a] = o;
            }
        }
    }
    __syncthreads();

    // ---- stage 3: conv2 via MFMA (C[d][(t,g)]) + bias + residual + LN2 + pack ----
    f32x4 acc2[2][4] = {};   // [mtl][nt]
#pragma unroll
    for (int it = 0; it < 24; ++it) {
        const int ktap = it >> 3, kk = it & 7;
        short8 cfr[2];
#pragma unroll
        for (int mtl = 0; mtl < 2; ++mtl)
            cfr[mtl] = *(const short8*)(w2p + it * 4096 + mtl * 512 + alane2);
        short8 bfr[4];
#pragma unroll
        for (int nt = 0; nt < 4; ++nt) {
            int rr = rowb[nt] + ktap;
            int mb = rr * 256 + ((rr >= 37) ? 256 : 0);
            int a  = mb + (((kk * 4 + quad) ^ (rr & 7)) << 3);
            bfr[nt] = *(const short8*)&uni[a];
        }
#pragma unroll
        for (int mtl = 0; mtl < 2; ++mtl)
#pragma unroll
            for (int nt = 0; nt < 4; ++nt)
                acc2[mtl][nt] = __builtin_amdgcn_mfma_f32_16x16x32_bf16(
                    cfr[mtl], bfr[nt], acc2[mtl][nt], 0, 0, 0);
    }
    // epilogue: val = conv2 + b2 + resid(x*gate+bias); LN2 over 1024/token
    {
        float vals[2][4][4];
        float s[4] = {0.f, 0.f, 0.f, 0.f}, ss[4] = {0.f, 0.f, 0.f, 0.f};
#pragma unroll
        for (int mtl = 0; mtl < 2; ++mtl) {
            int dq = w * 32 + mtl * 16 + quad * 4;
            float4 b2q = ld4<ISBF>(b2, dq);
#pragma unroll
            for (int nt = 0; nt < 4; ++nt) {
                int n = nt * 16 + col; int t = n >> 3, g = n & 7;
                int e = g * D + dq;
                float4 xr = ld4<ISBF>(x, (tok0 + t) * PK + e);
                float4 gq = *(const float4*)(gws + e);
                float4 bq = ld4<ISBF>(slot_bias, e);
#pragma unroll
                for (int r = 0; r < 4; ++r) {
                    float resid = f4c(xr, r) * f4c(gq, r) + f4c(bq, r);
                    float val = acc2[mtl][nt][r] + f4c(b2q, r) + resid;
                    vals[mtl][nt][r] = val;
                    s[nt] += val; ss[nt] += val * val;
                }
            }
        }
        // reduce over lanes sharing token t: masks {1,2,4,16,32}
#pragma unroll
        for (int nt = 0; nt < 4; ++nt) {
            s[nt] += __shfl_xor(s[nt], 1);  ss[nt] += __shfl_xor(ss[nt], 1);
            s[nt] += __shfl_xor(s[nt], 2);  ss[nt] += __shfl_xor(ss[nt], 2);
            s[nt] += __shfl_xor(s[nt], 4);  ss[nt] += __shfl_xor(ss[nt], 4);
            s[nt] += __shfl_xor(s[nt], 16); ss[nt] += __shfl_xor(ss[nt], 16);
            s[nt] += __shfl_xor(s[nt], 32); ss[nt] += __shfl_xor(ss[nt], 32);
        }
        if (quad == 0 && (col & 7) == 0) {
#pragma unroll
            for (int nt = 0; nt < 4; ++nt) {
                int t = 2 * nt + (col >> 3);
                red_s[t][w] = s[nt]; red_ss[t][w] = ss[nt];
            }
        }
        __syncthreads();
        float mean[4], rstd[4];
#pragma unroll
        for (int nt = 0; nt < 4; ++nt) {
            int t = 2 * nt + (col >> 3);
            float st  = red_s[t][0] + red_s[t][1] + red_s[t][2] + red_s[t][3];
            float sst = red_ss[t][0] + red_ss[t][1] + red_ss[t][2] + red_ss[t][3];
            mean[nt] = st * (1.f / 1024.f);
            float var = sst * (1.f / 1024.f) - mean[nt] * mean[nt];
            rstd[nt] = rsqrtf(var + 1e-5f);
        }
#pragma unroll
        for (int mtl = 0; mtl < 2; ++mtl) {
            int dq = w * 32 + mtl * 16 + quad * 4;
#pragma unroll
            for (int nt = 0; nt < 4; ++nt) {
                int n = nt * 16 + col; int t = n >> 3, g = n & 7;
                int e = g * D + dq;
                float4 pg4 = ld4<ISBF>(pack_g, e);
                float4 pb4 = ld4<ISBF>(pack_b, e);
                float zv[4];
#pragma unroll
                for (int r = 0; r < 4; ++r)
                    zv[r] = (vals[mtl][nt][r] - mean[nt]) * rstd[nt] * f4c(pg4, r)
                            + f4c(pb4, r);
                uint2 o;
                o.x = pk_bf16(zv[0], zv[1]);
                o.y = pk_bf16(zv[2], zv[3]);
                *(uint2*)(zout + (tok0 + t) * PK + e) = o;
            }
        }
    }
}

// ---------- z @ Wm + bm via MFMA, m97 structure (single buffer, 16KB LDS) ----------
// R7: launch_bounds (256,3) -> 3 blocks/CU (was (256,2) w/ 32KB dbuf = 2).
// Regs: 64 AGPR acc + ~80 VGPR ~= 144 <= 170 cap -> spill-free.
template <bool ISBF>
__global__ __launch_bounds__(256, 3)
void gemm_out(const u16* __restrict__ z, const u16* __restrict__ wmt,
              const void* __restrict__ bm, void* __restrict__ out,
              const int* __restrict__ flag) {
    if ((flag[0] != 0) != ISBF) return;
    __shared__ u16 As[128 * 32];   // z tile   [m][k] linear (gload_lds order)
    __shared__ u16 Bs[128 * 32];   // WmT tile [n][k] linear
    const int tid = threadIdx.x, lane = tid & 63, w = tid >> 6;
    const int quad = lane >> 4, col = lane & 15;
    // XCD-bijective swizzle (nwg = 1024, % 8 == 0)
    const int swz = ((blockIdx.x & 7) << 7) | ((int)blockIdx.x >> 3);
    const int bm0 = (swz >> 3) * 128, bn0 = (swz & 7) * 128;
    const int wm = w >> 1, wn = w & 1;
    const int c0 = w * 128 + lane;   // staging chunk base for this lane
    f32x4 acc[4][4] = {};            // [nt][mt]

    const u16* zrow0 = z   + (size_t)bm0 * DM;
    const u16* wrow0 = wmt + (size_t)bn0 * DM;

    for (int k0 = 0; k0 < DM; k0 += 32) {
#pragma unroll
        for (int q = 0; q < 2; ++q) {
            int c = c0 + q * 64;
            int r = c >> 2, kc = (c & 3) * 8;
            gload_lds16(zrow0 + (size_t)r * DM + k0 + kc, &As[(w * 2 + q) * 512]);
            gload_lds16(wrow0 + (size_t)r * DM + k0 + kc, &Bs[(w * 2 + q) * 512]);
        }
        __syncthreads();   // vmcnt(0) drain + barrier: tile ready
        short8 zfr[4], wfr[4];
#pragma unroll
        for (int mt = 0; mt < 4; ++mt)
            zfr[mt] = *(const short8*)&As[(wm * 64 + mt * 16 + col) * 32 + quad * 8];
#pragma unroll
        for (int nt = 0; nt < 4; ++nt)
            wfr[nt] = *(const short8*)&Bs[(wn * 64 + nt * 16 + col) * 32 + quad * 8];
#pragma unroll
        for (int nt = 0; nt < 4; ++nt)
#pragma unroll
            for (int mt = 0; mt < 4; ++mt)
                acc[nt][mt] = __builtin_amdgcn_mfma_f32_16x16x32_bf16(
                    wfr[nt], zfr[mt], acc[nt][mt], 0, 0, 0);
        __syncthreads();   // all reads done before next stage overwrites
    }
    // epilogue: C rows = n (quad*4+r), cols = m
#pragma unroll
    for (int nt = 0; nt < 4; ++nt) {
        int n = bn0 + wn * 64 + nt * 16 + quad * 4;
        float4 bq = ld4<ISBF>(bm, n);
#pragma unroll
        for (int mt = 0; mt < 4; ++mt) {
            int m = bm0 + wm * 64 + mt * 16 + col;
            float4 o = make_float4(acc[nt][mt][0] + bq.x, acc[nt][mt][1] + bq.y,
                                   acc[nt][mt][2] + bq.z, acc[nt][mt][3] + bq.w);
            st4<ISBF>(out, (size_t)m * DM + n, o);
        }
    }
}

// ---------- scalar fallback (R2-proven), raw weights ----------
template <bool ISBF>
__global__ __launch_bounds__(256)
void slotconv_scalar(const void* __restrict__ x,
                     const void* __restrict__ slot_gate,
                     const void* __restrict__ slot_bias,
                     const void* __restrict__ pre_g,
                     const void* __restrict__ pre_b,
                     const void* __restrict__ w1raw,
                     const void* __restrict__ b1,
                     const void* __restrict__ w2raw,
                     const void* __restrict__ b2,
                     const void* __restrict__ pack_g,
                     const void* __restrict__ pack_b,
                     const void* __restrict__ Wm,
                     const void* __restrict__ bm,
                     void* __restrict__ out,
                     const int* __restrict__ flag) {
    if ((flag[0] != 0) != ISBF) return;
    __shared__ float resid[G * D];
    __shared__ float xnpadf[(G + 2) * D];
    __shared__ float midpadf[(G + 2) * H];
    __shared__ float zbuf[4][PK];
    __shared__ float red[8];
    const int tid = threadIdx.x;
    if (tid < D) { xnpadf[tid] = 0.f; xnpadf[(G + 1) * D + tid] = 0.f; }
    midpadf[tid] = 0.f; midpadf[(G + 1) * H + tid] = 0.f;
    const int e0 = 4 * tid;
    const int d0 = e0 & (D - 1);
    const int g0 = tid >> 5;
    float gate[4], bias[4], pgf[4], pbf[4];
    {
        float4 sg4 = ld4<ISBF>(slot_gate, e0);
        float4 sb4 = ld4<ISBF>(slot_bias, e0);
        float4 pg4 = ld4<ISBF>(pre_g, d0);
        float4 pb4 = ld4<ISBF>(pre_b, d0);
#pragma unroll
        for (int j = 0; j < 4; ++j) {
            gate[j] = 2.f / (1.f + __expf(-f4c(sg4, j)));
            bias[j] = f4c(sb4, j);
            pgf[j] = f4c(pg4, j); pbf[j] = f4c(pb4, j);
        }
    }
    for (int t = 0; t < 4; ++t) {
        __syncthreads();
        const size_t tok = (size_t)blockIdx.x * 4 + t;
        {
            float4 x4 = ld4<ISBF>(x, tok * PK + e0);
            float v[4];
#pragma unroll
            for (int j = 0; j < 4; ++j) v[j] = f4c(x4, j) * gate[j] + bias[j];
            *(float4*)&resid[e0] = make_float4(v[0], v[1], v[2], v[3]);
            float s = v[0]+v[1]+v[2]+v[3], ss = v[0]*v[0]+v[1]*v[1]+v[2]*v[2]+v[3]*v[3];
#pragma unroll
            for (int m = 1; m < 32; m <<= 1) { s += __shfl_xor(s, m); ss += __shfl_xor(ss, m); }
            float mean = s * (1.f/128.f), var = ss * (1.f/128.f) - mean*mean;
            float rstd = rsqrtf(var + 1e-5f);
            float xn[4];
#pragma unroll
            for (int j = 0; j < 4; ++j) xn[j] = (v[j]-mean)*rstd*pgf[j]+pbf[j];
            *(float4*)&xnpadf[(g0+1)*D + d0] = make_float4(xn[0],xn[1],xn[2],xn[3]);
        }
        __syncthreads();
        {
            const int h = tid;
            float acc[G];
#pragma unroll
            for (int g = 0; g < G; ++g) acc[g] = 0.f;
            for (int d4 = 0; d4 < D; d4 += 4) {
                float4 xr4[G + 2];
#pragma unroll
                for (int r = 0; r < G + 2; ++r) xr4[r] = *(const float4*)&xnpadf[r * D + d4];
#pragma unroll
                for (int j = 0; j < 4; ++j) {
                    size_t o = (size_t)h * (D * 3) + (d4 + j) * 3;
                    float wk0 = ld1<ISBF>(w1raw, o), wk1 = ld1<ISBF>(w1raw, o+1), wk2 = ld1<ISBF>(w1raw, o+2);
#pragma unroll
                    for (int g = 0; g < G; ++g) {
                        acc[g] += f4c(xr4[g+0], j) * wk0;
                        acc[g] += f4c(xr4[g+1], j) * wk1;
                        acc[g] += f4c(xr4[g+2], j) * wk2;
                    }
                }
            }
            float b1h = ld1<ISBF>(b1, tid);
#pragma unroll
            for (int g = 0; g < G; ++g) {
                float m = acc[g] + b1h;
                midpadf[(g+1)*H + h] = 0.5f * m * (1.f + erff(m * 0.70710678118654752f));
            }
        }
        __syncthreads();
        {
            const int dd = tid & (D - 1);
            const int gh = tid >> 7;
            float acc2[4] = {0.f,0.f,0.f,0.f};
            for (int h4 = 0; h4 < H; h4 += 4) {
                float4 mr4[6];
#pragma unroll
                for (int r = 0; r < 6; ++r) mr4[r] = *(const float4*)&midpadf[(gh*4+r)*H + h4];
#pragma unroll
                for (int j = 0; j < 4; ++j) {
                    size_t o = (size_t)dd * (H * 3) + (h4 + j) * 3;
                    float wk0 = ld1<ISBF>(w2raw, o), wk1 = ld1<ISBF>(w2raw, o+1), wk2 = ld1<ISBF>(w2raw, o+2);
#pragma unroll
                    for (int jj = 0; jj < 4; ++jj) {
                        acc2[jj] += f4c(mr4[jj+0], j) * wk0;
                        acc2[jj] += f4c(mr4[jj+1], j) * wk1;
                        acc2[jj] += f4c(mr4[jj+2], j) * wk2;
                    }
                }
            }
            float b2d = ld1<ISBF>(b2, dd);
            float vz[4], s = 0.f, ss = 0.f;
#pragma unroll
            for (int j = 0; j < 4; ++j) {
                int e = (gh*4+j)*D + dd;
                float val = acc2[j] + b2d + resid[e];
                vz[j] = val; s += val; ss += val*val;
            }
#pragma unroll
            for (int m = 1; m < 64; m <<= 1) { s += __shfl_xor(s, m); ss += __shfl_xor(ss, m); }
            const int wid = tid >> 6;
            if ((tid & 63) == 0) { red[wid*2] = s; red[wid*2+1] = ss; }
            __syncthreads();
            float st = red[0]+red[2]+red[4]+red[6], sst = red[1]+red[3]+red[5]+red[7];
            float mean = st * (1.f/1024.f), var = sst * (1.f/1024.f) - mean*mean;
            float rstd = rsqrtf(var + 1e-5f);
#pragma unroll
            for (int j = 0; j < 4; ++j) {
                int e = (gh*4+j)*D + dd;
                zbuf[t][e] = (vz[j]-mean)*rstd*ld1<ISBF>(pack_g, e) + ld1<ISBF>(pack_b, e);
            }
        }
    }
    __syncthreads();
    {
        float accm[4][4];
#pragma unroll
        for (int t = 0; t < 4; ++t)
#pragma unroll
            for (int j = 0; j < 4; ++j) accm[t][j] = 0.f;
        for (int p4 = 0; p4 < PK; p4 += 4) {
            float4 z4[4];
#pragma unroll
            for (int t = 0; t < 4; ++t) z4[t] = *(const float4*)&zbuf[t][p4];
#pragma unroll
            for (int pp = 0; pp < 4; ++pp) {
                float4 w4 = ld4<ISBF>(Wm, (size_t)(p4 + pp) * DM + e0);
#pragma unroll
                for (int t = 0; t < 4; ++t) {
                    float zp = f4c(z4[t], pp);
                    accm[t][0] += zp * w4.x; accm[t][1] += zp * w4.y;
                    accm[t][2] += zp * w4.z; accm[t][3] += zp * w4.w;
                }
            }
        }
        float4 bm4 = ld4<ISBF>(bm, e0);
#pragma unroll
        for (int t = 0; t < 4; ++t) {
            const size_t tok = (size_t)blockIdx.x * 4 + t;
            st4<ISBF>(out, tok * DM + e0,
                      make_float4(accm[t][0]+bm4.x, accm[t][1]+bm4.y,
                                  accm[t][2]+bm4.z, accm[t][3]+bm4.w));
        }
    }
}

extern "C" void kernel_launch(void* const* d_in, const int* in_sizes, int n_in,
                              void* d_out, int out_size, void* d_ws, size_t ws_size,
                              hipStream_t stream) {
    const void* x   = d_in[0];
    const void* sg  = d_in[1];
    const void* sb  = d_in[2];
    const void* pg  = d_in[3];
    const void* pb  = d_in[4];
    const void* w1  = d_in[5];
    const void* b1  = d_in[6];
    const void* w2  = d_in[7];
    const void* b2  = d_in[8];
    const void* pkg = d_in[9];
    const void* pkb = d_in[10];
    const void* Wm  = d_in[11];
    const void* bm  = d_in[12];

    int* flag = (int*)d_ws;
    u16* base = (u16*)((char*)d_ws + 16);
    u16* w1p = base;                       // 98304 el
    u16* w2p = base + 98304;               // 98304 el
    u16* wmt = base + 196608;              // 1048576 el
    u16* zws = base + 196608 + 1048576;    // 16777216 el
    float* gws = (float*)(base + 18022400);          // 1024 f32
    const size_t ws_needed = 16 + (size_t)18022400 * sizeof(u16) + PK * sizeof(float);

    detect_dtype<<<1, 256, 0, stream>>>(x, flag);

    if (ws_size >= ws_needed) {
        prep_mfma<true ><<<640, 256, 0, stream>>>(w1, w2, Wm, sg, w1p, w2p, wmt, gws, flag);
        prep_mfma<false><<<640, 256, 0, stream>>>(w1, w2, Wm, sg, w1p, w2p, wmt, gws, flag);
        conv_fused<true ><<<NTOK / 8, 256, 0, stream>>>(x, sb, pg, pb, b1, b2, pkg, pkb, w1p, w2p, gws, zws, flag);
        conv_fused<false><<<NTOK / 8, 256, 0, stream>>>(x, sb, pg, pb, b1, b2, pkg, pkb, w1p, w2p, gws, zws, flag);
        gemm_out<true ><<<(NTOK / 128) * (DM / 128), 256, 0, stream>>>(zws, wmt, bm, d_out, flag);
        gemm_out<false><<<(NTOK / 128) * (DM / 128), 256, 0, stream>>>(zws, wmt, bm, d_out, flag);
    } else {
        slotconv_scalar<true ><<<NTOK / 4, 256, 0, stream>>>(
            x, sg, sb, pg, pb, w1, b1, w2, b2, pkg, pkb, Wm, bm, d_out, flag);
        slotconv_scalar<false><<<NTOK / 4, 256, 0, stream>>>(
            x, sg, sb, pg, pb, w1, b1, w2, b2, pkg, pkb, Wm, bm, d_out, flag);
    }
}

// Round 8
// 291.002 us; speedup vs baseline: 1.0659x; 1.0313x over previous
//
#include <hip/hip_runtime.h>
#include <hip/hip_bf16.h>
#include <math.h>

typedef unsigned short u16;
typedef unsigned int   u32;
typedef __attribute__((ext_vector_type(8))) short short8;   // 8 bf16
typedef __attribute__((ext_vector_type(4))) float f32x4;    // MFMA acc

// Problem constants
constexpr int G  = 8;
constexpr int D  = 128;
constexpr int H  = 256;
constexpr int DM = 1024;
constexpr int PK = 1024;
constexpr int NTOK = 8 * 2048;   // 16384

// ---------- scalar helpers ----------
__device__ __forceinline__ float bf2f(u16 u) {
    union { u32 i; float f; } v; v.i = ((u32)u) << 16; return v.f;
}
__device__ __forceinline__ u16 f2bf(float f) {
    union { float f; u32 i; } v; v.f = f;
    u32 x = v.i;
    return (u16)((x + 0x7fffu + ((x >> 16) & 1u)) >> 16);  // RNE
}
// packed f32x2 -> bf16x2 (RNE), single VALU op
__device__ __forceinline__ u32 pk_bf16(float lo, float hi) {
    u32 d;
    asm("v_cvt_pk_bf16_f32 %0, %1, %2" : "=v"(d) : "v"(lo), "v"(hi));
    return d;
}
__device__ __forceinline__ float f4c(const float4 v, int j) {
    return j == 0 ? v.x : j == 1 ? v.y : j == 2 ? v.z : v.w;
}
template <bool ISBF>
__device__ __forceinline__ float ld1(const void* p, size_t i) {
    if (ISBF) return bf2f(((const u16*)p)[i]);
    else      return ((const float*)p)[i];
}
template <bool ISBF>
__device__ __forceinline__ float4 ld4(const void* p, size_t i) {  // i % 4 == 0
    if (ISBF) {
        ushort4 v = *(const ushort4*)((const u16*)p + i);
        return make_float4(bf2f(v.x), bf2f(v.y), bf2f(v.z), bf2f(v.w));
    } else {
        return *(const float4*)((const float*)p + i);
    }
}
template <bool ISBF>
__device__ __forceinline__ void st4(void* p, size_t i, float4 v) {
    if (ISBF) {
        ushort4 o; o.x = f2bf(v.x); o.y = f2bf(v.y); o.z = f2bf(v.z); o.w = f2bf(v.w);
        *(ushort4*)((u16*)p + i) = o;
    } else {
        *(float4*)((float*)p + i) = v;
    }
}
// tanh-form GELU (max dev vs exact erf-GELU ~3e-4, tolerance 6.4e-2)
__device__ __forceinline__ float gelu_f(float v) {
    float u = v * (0.7978845608028654f + 0.0356774081f * v * v);
    float e = __expf(2.f * u);
    float th = 1.f - 2.f / (e + 1.f);
    return 0.5f * v * (1.f + th);
}
// async global->LDS, 16B per lane; LDS dest = wave-uniform base + lane*16
__device__ __forceinline__ void gload_lds16(const void* gp, void* lp) {
    __builtin_amdgcn_global_load_lds(
        (const __attribute__((address_space(1))) void*)gp,
        (__attribute__((address_space(3))) void*)lp, 16, 0, 0);
}

// ---------- dtype detect (proven R2) ----------
__global__ void detect_dtype(const void* xraw, int* flag) {
    __shared__ int cnt[256];
    const u32* xw = (const u32*)xraw;
    int tid = threadIdx.x, c = 0;
#pragma unroll
    for (int k = 0; k < 4; ++k) {
        u32 w = xw[tid * 4 + k];
#pragma unroll
        for (int h = 0; h < 2; ++h) {
            u16 u = (u16)(w >> (16 * h));
            int e = (u >> 7) & 0xFF;
            if ((u & 0x7FFF) == 0 || (e >= 112 && e <= 143)) ++c;
        }
    }
    cnt[tid] = c;
    __syncthreads();
    for (int s = 128; s > 0; s >>= 1) {
        if (tid < s) cnt[tid] += cnt[tid + s];
        __syncthreads();
    }
    if (tid == 0) flag[0] = (cnt[0] >= 1900) ? 1 : 0;
}

// ---------- MFMA-path weight prep ----------
// blocks [0,256): Wm -> wmt (WmT, bf16) via LDS 64x64 tile transpose
// blocks [256,640): fragment-major conv weights + gws.
//   w1p[((ktap*4+kk)*256 + h)*32 + j]  = w1[h][kk*32+j][ktap]   (j in [0,32))
//   w2p[((ktap*8+kk)*128 + d)*32 + j]  = w2[d][kk*32+j][ktap]
template <bool ISBF>
__global__ __launch_bounds__(256)
void prep_mfma(const void* __restrict__ w1, const void* __restrict__ w2,
               const void* __restrict__ Wm, const void* __restrict__ slot_gate,
               u16* __restrict__ w1p, u16* __restrict__ w2p,
               u16* __restrict__ wmt, float* __restrict__ gws,
               const int* __restrict__ flag) {
    if ((flag[0] != 0) != ISBF) return;
    __shared__ u16 tile[64][72];
    const int tid = threadIdx.x;
    if (blockIdx.x < 256) {
        const int kk0 = (blockIdx.x >> 4) * 64, n0 = (blockIdx.x & 15) * 64;
        const int r = tid >> 2, q = tid & 3;
#pragma unroll
        for (int j4 = 0; j4 < 4; ++j4) {
            float4 v = ld4<ISBF>(Wm, (size_t)(kk0 + r) * DM + n0 + q * 16 + j4 * 4);
            tile[r][q * 16 + j4 * 4 + 0] = f2bf(v.x);
            tile[r][q * 16 + j4 * 4 + 1] = f2bf(v.y);
            tile[r][q * 16 + j4 * 4 + 2] = f2bf(v.z);
            tile[r][q * 16 + j4 * 4 + 3] = f2bf(v.w);
        }
        __syncthreads();
        u16 op[16];
#pragma unroll
        for (int j = 0; j < 16; ++j) op[j] = tile[q * 16 + j][r];
        u16* dst = wmt + (size_t)(n0 + r) * DM + kk0 + q * 16;
        *(short8*)dst       = *(const short8*)&op[0];
        *(short8*)(dst + 8) = *(const short8*)&op[8];
        return;
    }
    int idx = (blockIdx.x - 256) * 256 + tid;
    if (idx < 3 * 4 * H * 32) {          // 98304 for each of w1p/w2p
        int jq = idx & 31;
        int t2 = idx >> 5;
        // w1p: t2 = (ktap*4+kk)*256 + h
        int h  = t2 & (H - 1);
        int ik = t2 >> 8;                // 0..11
        int kt1 = ik >> 2, kk1 = ik & 3;
        int dd = kk1 * 32 + jq;
        w1p[idx] = f2bf(ld1<ISBF>(w1, (size_t)(h * D + dd) * 3 + kt1));
        // w2p: t2 = (ktap*8+kk)*128 + d
        int d   = t2 & (D - 1);
        int ik2 = t2 >> 7;               // 0..23
        int kt2 = ik2 >> 3, kk2 = ik2 & 7;
        int hh = kk2 * 32 + jq;
        w2p[idx] = f2bf(ld1<ISBF>(w2, (size_t)(d * H + hh) * 3 + kt2));
    }
    if (idx < PK) gws[idx] = 2.f / (1.f + __expf(-ld1<ISBF>(slot_gate, idx)));
}

// ---------- fused gate+LN1+conv1+GELU+conv2+LN2 -> z (bf16) ----------
// 8 tokens/block, 256 threads (4 waves), 16x16x32 bf16 MFMA.
// conv1 split into two nt-passes (32-AGPR live acc) -> fits (256,3), no spill.
// PROVEN R5/R7: (256,3) -> VGPR 80, WRITE 33MB (clean), ~135 us. (256,4)
// spills (R6: 128-reg cap < ~140 footprint -> WRITE 78MB, 146 us). Keep.
// LDS union uni[74*256 u16] (37888 B):
//   xnpad  rows 0..72  : u16 base r*128            (u16 idx 0..9343)
//   midpad rows 0..36  : u16 base r*256            [M_lo]
//   midpad rows 37..72 : u16 base r*256+256        [M_hi, idx 9728..18943]
template <bool ISBF>
__global__ __launch_bounds__(256, 3)
void conv_fused(const void* __restrict__ x,
                const void* __restrict__ slot_bias,
                const void* __restrict__ pre_g,
                const void* __restrict__ pre_b,
                const void* __restrict__ b1,
                const void* __restrict__ b2,
                const void* __restrict__ pack_g,
                const void* __restrict__ pack_b,
                const u16* __restrict__ w1p,
                const u16* __restrict__ w2p,
                const float* __restrict__ gws,
                u16* __restrict__ zout,
                const int* __restrict__ flag) {
    if ((flag[0] != 0) != ISBF) return;

    __shared__ u16 uni[74 * 256];          // 37888 B union
    __shared__ float red_s[8][4], red_ss[8][4];

    const int tid  = threadIdx.x;
    const int lane = tid & 63, w = tid >> 6;
    const int quad = lane >> 4, col = lane & 15;
    const size_t tok0 = (size_t)blockIdx.x * 8;

    // ---- stage 0: zero xnpad halo rows (9 x 128) + M_hi halo rows {45,54,63,72} ----
    if (tid < 72) {
        int li = tid * 16, hr = li >> 7, e = li & 127;   // 8 threads/row, 16 u16 each
        u16* p = &uni[hr * 9 * 128 + e];
#pragma unroll
        for (int q = 0; q < 4; ++q) *(ushort4*)(p + 4 * q) = make_ushort4(0, 0, 0, 0);
    } else if (tid >= 128) {
        int li = (tid - 128) * 8, hr = li >> 8, e = li & 255;  // 32 threads/row, 8 u16
        int row = 45 + hr * 9;                       // 45,54,63,72
        u16* p = &uni[row * 256 + 256 + e];          // M_hi mapping
        *(ushort4*)p       = make_ushort4(0, 0, 0, 0);
        *(ushort4*)(p + 4) = make_ushort4(0, 0, 0, 0);
    }

    // per-thread slice for stage 1
    const int e0 = 4 * tid;
    const int d0 = e0 & (D - 1);
    const int g0 = tid >> 5;
    float gf[4], bff[4], pgf[4], pbf[4];
    {
        float4 gg  = *(const float4*)(gws + e0);        // precomputed 2*sigmoid, f32
        float4 sb4 = ld4<ISBF>(slot_bias, e0);
        float4 pg4 = ld4<ISBF>(pre_g, d0);
        float4 pb4 = ld4<ISBF>(pre_b, d0);
#pragma unroll
        for (int j = 0; j < 4; ++j) {
            gf[j]  = f4c(gg, j);
            bff[j] = f4c(sb4, j);
            pgf[j] = f4c(pg4, j);
            pbf[j] = f4c(pb4, j);
        }
    }

    // ---- stage 1: gate+bias, LN1, write xn (bf16, swizzled) ----
#pragma unroll
    for (int t = 0; t < 8; ++t) {
        float4 x4 = ld4<ISBF>(x, (tok0 + t) * PK + e0);
        float v[4];
#pragma unroll
        for (int j = 0; j < 4; ++j) v[j] = f4c(x4, j) * gf[j] + bff[j];
        float s = v[0] + v[1] + v[2] + v[3];
        float ss = v[0]*v[0] + v[1]*v[1] + v[2]*v[2] + v[3]*v[3];
#pragma unroll
        for (int m = 1; m < 32; m <<= 1) {
            s  += __shfl_xor(s,  m);
            ss += __shfl_xor(ss, m);
        }
        float mean = s * (1.f / 128.f);
        float var  = ss * (1.f / 128.f) - mean * mean;
        float rstd = rsqrtf(var + 1e-5f);
        uint2 o;
        o.x = pk_bf16((v[0] - mean) * rstd * pgf[0] + pbf[0],
                      (v[1] - mean) * rstd * pgf[1] + pbf[1]);
        o.y = pk_bf16((v[2] - mean) * rstd * pgf[2] + pbf[2],
                      (v[3] - mean) * rstd * pgf[3] + pbf[3]);
        int row  = t * 9 + g0 + 1;
        int addr = row * 128 + (((d0 >> 3) ^ (row & 7)) << 3) + (d0 & 7);
        *(uint2*)&uni[addr] = o;
    }
    __syncthreads();

    // per-lane (t,g) base rows for the 4 N-tiles (shared by conv1/conv2)
    int rowb[4];
#pragma unroll
    for (int nt = 0; nt < 4; ++nt) {
        int n = nt * 16 + col;
        rowb[nt] = (n >> 3) * 9 + (n & 7);   // row for tap0; +ktap walks g-1,g,g+1
    }
    const int alane1 = (w * 64 + col) * 32 + quad * 8;   // conv1 per-lane weight off
    const int alane2 = (w * 32 + col) * 32 + quad * 8;   // conv2

    // ---- stage 2: conv1 via MFMA, two nt-passes (32-AGPR live acc each) ----
#pragma unroll
    for (int pass = 0; pass < 2; ++pass) {
        const int ntb = (pass == 0) ? 2 : 0;     // pass0: t4..7, pass1: t0..3
        f32x4 acc[4][2] = {};                     // [mtl][ntl]
#pragma unroll
        for (int it = 0; it < 12; ++it) {
            const int ktap = it >> 2, kk = it & 3;
            short8 afr[4];
#pragma unroll
            for (int mtl = 0; mtl < 4; ++mtl)
                afr[mtl] = *(const short8*)(w1p + it * 8192 + mtl * 512 + alane1);
            short8 bfr[2];
#pragma unroll
            for (int ntl = 0; ntl < 2; ++ntl) {
                int rr = rowb[ntb + ntl] + ktap;
                int a  = rr * 128 + (((kk * 4 + quad) ^ (rr & 7)) << 3);
                bfr[ntl] = *(const short8*)&uni[a];
            }
#pragma unroll
            for (int mtl = 0; mtl < 4; ++mtl)
#pragma unroll
                for (int ntl = 0; ntl < 2; ++ntl)
                    acc[mtl][ntl] = __builtin_amdgcn_mfma_f32_16x16x32_bf16(
                        afr[mtl], bfr[ntl], acc[mtl][ntl], 0, 0, 0);
        }
        if (pass == 1) {
            // all waves done reading xnpad -> safe to overlay M_lo
            __syncthreads();
            // zero M_lo halo rows {0,9,18,27,36}
            if (tid < 160) {
                int li = tid * 8, hr = li >> 8, e = li & 255;
                u16* p = &uni[hr * 9 * 256 + e];   // rows {0,9,18,27,36}, M_lo map
                *(ushort4*)p       = make_ushort4(0, 0, 0, 0);
                *(ushort4*)(p + 4) = make_ushort4(0, 0, 0, 0);
            }
        }
        // epilogue: bias + GELU -> midpad (swizzled); pass0 rows>=37 (M_hi)
#pragma unroll
        for (int mtl = 0; mtl < 4; ++mtl) {
            int hq = w * 64 + mtl * 16 + quad * 4;
            float4 b1q = ld4<ISBF>(b1, hq);
#pragma unroll
            for (int ntl = 0; ntl < 2; ++ntl) {
                int row = rowb[ntb + ntl] + 1;
                uint2 o;
                o.x = pk_bf16(gelu_f(acc[mtl][ntl][0] + b1q.x),
                              gelu_f(acc[mtl][ntl][1] + b1q.y));
                o.y = pk_bf16(gelu_f(acc[mtl][ntl][2] + b1q.z),
                              gelu_f(acc[mtl][ntl][3] + b1q.w));
                int mb = row * 256 + ((row >= 37) ? 256 : 0);
                int a  = mb + (((hq >> 3) ^ (row & 7)) << 3) + (hq & 7);
                *(uint2*)&uni[a] = o;
            }
        }
    }
    __syncthreads();

    // ---- stage 3: conv2 via MFMA (C[d][(t,g)]) + bias + residual + LN2 + pack ----
    f32x4 acc2[2][4] = {};   // [mtl][nt]
#pragma unroll
    for (int it = 0; it < 24; ++it) {
        const int ktap = it >> 3, kk = it & 7;
        short8 cfr[2];
#pragma unroll
        for (int mtl = 0; mtl < 2; ++mtl)
            cfr[mtl] = *(const short8*)(w2p + it * 4096 + mtl * 512 + alane2);
        short8 bfr[4];
#pragma unroll
        for (int nt = 0; nt < 4; ++nt) {
            int rr = rowb[nt] + ktap;
            int mb = rr * 256 + ((rr >= 37) ? 256 : 0);
            int a  = mb + (((kk * 4 + quad) ^ (rr & 7)) << 3);
            bfr[nt] = *(const short8*)&uni[a];
        }
#pragma unroll
        for (int mtl = 0; mtl < 2; ++mtl)
#pragma unroll
            for (int nt = 0; nt < 4; ++nt)
                acc2[mtl][nt] = __builtin_amdgcn_mfma_f32_16x16x32_bf16(
                    cfr[mtl], bfr[nt], acc2[mtl][nt], 0, 0, 0);
    }
    // epilogue: val = conv2 + b2 + resid(x*gate+bias); LN2 over 1024/token
    {
        float vals[2][4][4];
        float s[4] = {0.f, 0.f, 0.f, 0.f}, ss[4] = {0.f, 0.f, 0.f, 0.f};
#pragma unroll
        for (int mtl = 0; mtl < 2; ++mtl) {
            int dq = w * 32 + mtl * 16 + quad * 4;
            float4 b2q = ld4<ISBF>(b2, dq);
#pragma unroll
            for (int nt = 0; nt < 4; ++nt) {
                int n = nt * 16 + col; int t = n >> 3, g = n & 7;
                int e = g * D + dq;
                float4 xr = ld4<ISBF>(x, (tok0 + t) * PK + e);
                float4 gq = *(const float4*)(gws + e);
                float4 bq = ld4<ISBF>(slot_bias, e);
#pragma unroll
                for (int r = 0; r < 4; ++r) {
                    float resid = f4c(xr, r) * f4c(gq, r) + f4c(bq, r);
                    float val = acc2[mtl][nt][r] + f4c(b2q, r) + resid;
                    vals[mtl][nt][r] = val;
                    s[nt] += val; ss[nt] += val * val;
                }
            }
        }
        // reduce over lanes sharing token t: masks {1,2,4,16,32}
#pragma unroll
        for (int nt = 0; nt < 4; ++nt) {
            s[nt] += __shfl_xor(s[nt], 1);  ss[nt] += __shfl_xor(ss[nt], 1);
            s[nt] += __shfl_xor(s[nt], 2);  ss[nt] += __shfl_xor(ss[nt], 2);
            s[nt] += __shfl_xor(s[nt], 4);  ss[nt] += __shfl_xor(ss[nt], 4);
            s[nt] += __shfl_xor(s[nt], 16); ss[nt] += __shfl_xor(ss[nt], 16);
            s[nt] += __shfl_xor(s[nt], 32); ss[nt] += __shfl_xor(ss[nt], 32);
        }
        if (quad == 0 && (col & 7) == 0) {
#pragma unroll
            for (int nt = 0; nt < 4; ++nt) {
                int t = 2 * nt + (col >> 3);
                red_s[t][w] = s[nt]; red_ss[t][w] = ss[nt];
            }
        }
        __syncthreads();
        float mean[4], rstd[4];
#pragma unroll
        for (int nt = 0; nt < 4; ++nt) {
            int t = 2 * nt + (col >> 3);
            float st  = red_s[t][0] + red_s[t][1] + red_s[t][2] + red_s[t][3];
            float sst = red_ss[t][0] + red_ss[t][1] + red_ss[t][2] + red_ss[t][3];
            mean[nt] = st * (1.f / 1024.f);
            float var = sst * (1.f / 1024.f) - mean[nt] * mean[nt];
            rstd[nt] = rsqrtf(var + 1e-5f);
        }
#pragma unroll
        for (int mtl = 0; mtl < 2; ++mtl) {
            int dq = w * 32 + mtl * 16 + quad * 4;
#pragma unroll
            for (int nt = 0; nt < 4; ++nt) {
                int n = nt * 16 + col; int t = n >> 3, g = n & 7;
                int e = g * D + dq;
                float4 pg4 = ld4<ISBF>(pack_g, e);
                float4 pb4 = ld4<ISBF>(pack_b, e);
                float zv[4];
#pragma unroll
                for (int r = 0; r < 4; ++r)
                    zv[r] = (vals[mtl][nt][r] - mean[nt]) * rstd[nt] * f4c(pg4, r)
                            + f4c(pb4, r);
                uint2 o;
                o.x = pk_bf16(zv[0], zv[1]);
                o.y = pk_bf16(zv[2], zv[3]);
                *(uint2*)(zout + (tok0 + t) * PK + e) = o;
            }
        }
    }
}

// ---------- z @ Wm + bm via MFMA ----------
// R8: BK=64 (16 K-steps, 32 MFMA per barrier-drain — half the drains of BK=32)
// + T2 chunk-XOR swizzle done BOTH-sides-or-neither (rule #21):
//   LDS dest stays LINEAR (global_load_lds requirement); the global SOURCE
//   16B-chunk index is pre-swizzled (j ^= r&7); reads apply the same XOR.
//   Bank math: byte = row*128 + (chunk^(row&7))*16 -> bank spread over 8
//   groups across 8 consecutive rows -> 2-way (free) vs old 8-way.
// LDS 2x16KB = 32KB; (256,3): 64 AGPR + ~90 VGPR fits 170-reg cap, no spill.
template <bool ISBF>
__global__ __launch_bounds__(256, 3)
void gemm_out(const u16* __restrict__ z, const u16* __restrict__ wmt,
              const void* __restrict__ bm, void* __restrict__ out,
              const int* __restrict__ flag) {
    if ((flag[0] != 0) != ISBF) return;
    __shared__ u16 As[128 * 64];   // z tile   [m][k], chunk-swizzled contents
    __shared__ u16 Bs[128 * 64];   // WmT tile [n][k], chunk-swizzled contents
    const int tid = threadIdx.x, lane = tid & 63, w = tid >> 6;
    const int quad = lane >> 4, col = lane & 15;
    // XCD-bijective swizzle (nwg = 1024, % 8 == 0)
    const int swz = ((blockIdx.x & 7) << 7) | ((int)blockIdx.x >> 3);
    const int bm0 = (swz >> 3) * 128, bn0 = (swz & 7) * 128;
    const int wm = w >> 1, wn = w & 1;
    f32x4 acc[4][4] = {};            // [nt][mt]

    const u16* zrow0 = z   + (size_t)bm0 * DM;
    const u16* wrow0 = wmt + (size_t)bn0 * DM;

    for (int k0 = 0; k0 < DM; k0 += 64) {
        // stage 128x64 for A and B: 1024 chunks of 16B each, 4 per thread.
        // LDS dest linear (chunk c at byte c*16); source chunk pre-swizzled.
#pragma unroll
        for (int q = 0; q < 4; ++q) {
            int c = q * 256 + tid;
            int r = c >> 3;                    // row 0..127
            int jj = (c & 7) ^ (r & 7);        // pre-swizzled source chunk
            const int ldsoff = (q * 256 + w * 64) * 8;   // wave-uniform, u16
            gload_lds16(zrow0 + (size_t)r * DM + k0 + jj * 8, &As[ldsoff]);
            gload_lds16(wrow0 + (size_t)r * DM + k0 + jj * 8, &Bs[ldsoff]);
        }
        __syncthreads();   // vmcnt(0) drain + barrier: tile ready
#pragma unroll
        for (int kk = 0; kk < 2; ++kk) {
            short8 zfr[4], wfr[4];
#pragma unroll
            for (int mt = 0; mt < 4; ++mt) {
                int row = wm * 64 + mt * 16 + col;
                zfr[mt] = *(const short8*)
                    &As[row * 64 + (((kk * 4 + quad) ^ (row & 7)) << 3)];
            }
#pragma unroll
            for (int nt = 0; nt < 4; ++nt) {
                int row = wn * 64 + nt * 16 + col;
                wfr[nt] = *(const short8*)
                    &Bs[row * 64 + (((kk * 4 + quad) ^ (row & 7)) << 3)];
            }
#pragma unroll
            for (int nt = 0; nt < 4; ++nt)
#pragma unroll
                for (int mt = 0; mt < 4; ++mt)
                    acc[nt][mt] = __builtin_amdgcn_mfma_f32_16x16x32_bf16(
                        wfr[nt], zfr[mt], acc[nt][mt], 0, 0, 0);
        }
        __syncthreads();   // all reads done before next stage overwrites
    }
    // epilogue: C rows = n (quad*4+r), cols = m
#pragma unroll
    for (int nt = 0; nt < 4; ++nt) {
        int n = bn0 + wn * 64 + nt * 16 + quad * 4;
        float4 bq = ld4<ISBF>(bm, n);
#pragma unroll
        for (int mt = 0; mt < 4; ++mt) {
            int m = bm0 + wm * 64 + mt * 16 + col;
            float4 o = make_float4(acc[nt][mt][0] + bq.x, acc[nt][mt][1] + bq.y,
                                   acc[nt][mt][2] + bq.z, acc[nt][mt][3] + bq.w);
            st4<ISBF>(out, (size_t)m * DM + n, o);
        }
    }
}

// ---------- scalar fallback (R2-proven), raw weights ----------
template <bool ISBF>
__global__ __launch_bounds__(256)
void slotconv_scalar(const void* __restrict__ x,
                     const void* __restrict__ slot_gate,
                     const void* __restrict__ slot_bias,
                     const void* __restrict__ pre_g,
                     const void* __restrict__ pre_b,
                     const void* __restrict__ w1raw,
                     const void* __restrict__ b1,
                     const void* __restrict__ w2raw,
                     const void* __restrict__ b2,
                     const void* __restrict__ pack_g,
                     const void* __restrict__ pack_b,
                     const void* __restrict__ Wm,
                     const void* __restrict__ bm,
                     void* __restrict__ out,
                     const int* __restrict__ flag) {
    if ((flag[0] != 0) != ISBF) return;
    __shared__ float resid[G * D];
    __shared__ float xnpadf[(G + 2) * D];
    __shared__ float midpadf[(G + 2) * H];
    __shared__ float zbuf[4][PK];
    __shared__ float red[8];
    const int tid = threadIdx.x;
    if (tid < D) { xnpadf[tid] = 0.f; xnpadf[(G + 1) * D + tid] = 0.f; }
    midpadf[tid] = 0.f; midpadf[(G + 1) * H + tid] = 0.f;
    const int e0 = 4 * tid;
    const int d0 = e0 & (D - 1);
    const int g0 = tid >> 5;
    float gate[4], bias[4], pgf[4], pbf[4];
    {
        float4 sg4 = ld4<ISBF>(slot_gate, e0);
        float4 sb4 = ld4<ISBF>(slot_bias, e0);
        float4 pg4 = ld4<ISBF>(pre_g, d0);
        float4 pb4 = ld4<ISBF>(pre_b, d0);
#pragma unroll
        for (int j = 0; j < 4; ++j) {
            gate[j] = 2.f / (1.f + __expf(-f4c(sg4, j)));
            bias[j] = f4c(sb4, j);
            pgf[j] = f4c(pg4, j); pbf[j] = f4c(pb4, j);
        }
    }
    for (int t = 0; t < 4; ++t) {
        __syncthreads();
        const size_t tok = (size_t)blockIdx.x * 4 + t;
        {
            float4 x4 = ld4<ISBF>(x, tok * PK + e0);
            float v[4];
#pragma unroll
            for (int j = 0; j < 4; ++j) v[j] = f4c(x4, j) * gate[j] + bias[j];
            *(float4*)&resid[e0] = make_float4(v[0], v[1], v[2], v[3]);
            float s = v[0]+v[1]+v[2]+v[3], ss = v[0]*v[0]+v[1]*v[1]+v[2]*v[2]+v[3]*v[3];
#pragma unroll
            for (int m = 1; m < 32; m <<= 1) { s += __shfl_xor(s, m); ss += __shfl_xor(ss, m); }
            float mean = s * (1.f/128.f), var = ss * (1.f/128.f) - mean*mean;
            float rstd = rsqrtf(var + 1e-5f);
            float xn[4];
#pragma unroll
            for (int j = 0; j < 4; ++j) xn[j] = (v[j]-mean)*rstd*pgf[j]+pbf[j];
            *(float4*)&xnpadf[(g0+1)*D + d0] = make_float4(xn[0],xn[1],xn[2],xn[3]);
        }
        __syncthreads();
        {
            const int h = tid;
            float acc[G];
#pragma unroll
            for (int g = 0; g < G; ++g) acc[g] = 0.f;
            for (int d4 = 0; d4 < D; d4 += 4) {
                float4 xr4[G + 2];
#pragma unroll
                for (int r = 0; r < G + 2; ++r) xr4[r] = *(const float4*)&xnpadf[r * D + d4];
#pragma unroll
                for (int j = 0; j < 4; ++j) {
                    size_t o = (size_t)h * (D * 3) + (d4 + j) * 3;
                    float wk0 = ld1<ISBF>(w1raw, o), wk1 = ld1<ISBF>(w1raw, o+1), wk2 = ld1<ISBF>(w1raw, o+2);
#pragma unroll
                    for (int g = 0; g < G; ++g) {
                        acc[g] += f4c(xr4[g+0], j) * wk0;
                        acc[g] += f4c(xr4[g+1], j) * wk1;
                        acc[g] += f4c(xr4[g+2], j) * wk2;
                    }
                }
            }
            float b1h = ld1<ISBF>(b1, tid);
#pragma unroll
            for (int g = 0; g < G; ++g) {
                float m = acc[g] + b1h;
                midpadf[(g+1)*H + h] = 0.5f * m * (1.f + erff(m * 0.70710678118654752f));
            }
        }
        __syncthreads();
        {
            const int dd = tid & (D - 1);
            const int gh = tid >> 7;
            float acc2[4] = {0.f,0.f,0.f,0.f};
            for (int h4 = 0; h4 < H; h4 += 4) {
                float4 mr4[6];
#pragma unroll
                for (int r = 0; r < 6; ++r) mr4[r] = *(const float4*)&midpadf[(gh*4+r)*H + h4];
#pragma unroll
                for (int j = 0; j < 4; ++j) {
                    size_t o = (size_t)dd * (H * 3) + (h4 + j) * 3;
                    float wk0 = ld1<ISBF>(w2raw, o), wk1 = ld1<ISBF>(w2raw, o+1), wk2 = ld1<ISBF>(w2raw, o+2);
#pragma unroll
                    for (int jj = 0; jj < 4; ++jj) {
                        acc2[jj] += f4c(mr4[jj+0], j) * wk0;
                        acc2[jj] += f4c(mr4[jj+1], j) * wk1;
                        acc2[jj] += f4c(mr4[jj+2], j) * wk2;
                    }
                }
            }
            float b2d = ld1<ISBF>(b2, dd);
            float vz[4], s = 0.f, ss = 0.f;
#pragma unroll
            for (int j = 0; j < 4; ++j) {
                int e = (gh*4+j)*D + dd;
                float val = acc2[j] + b2d + resid[e];
                vz[j] = val; s += val; ss += val*val;
            }
#pragma unroll
            for (int m = 1; m < 64; m <<= 1) { s += __shfl_xor(s, m); ss += __shfl_xor(ss, m); }
            const int wid = tid >> 6;
            if ((tid & 63) == 0) { red[wid*2] = s; red[wid*2+1] = ss; }
            __syncthreads();
            float st = red[0]+red[2]+red[4]+red[6], sst = red[1]+red[3]+red[5]+red[7];
            float mean = st * (1.f/1024.f), var = sst * (1.f/1024.f) - mean*mean;
            float rstd = rsqrtf(var + 1e-5f);
#pragma unroll
            for (int j = 0; j < 4; ++j) {
                int e = (gh*4+j)*D + dd;
                zbuf[t][e] = (vz[j]-mean)*rstd*ld1<ISBF>(pack_g, e) + ld1<ISBF>(pack_b, e);
            }
        }
    }
    __syncthreads();
    {
        float accm[4][4];
#pragma unroll
        for (int t = 0; t < 4; ++t)
#pragma unroll
            for (int j = 0; j < 4; ++j) accm[t][j] = 0.f;
        for (int p4 = 0; p4 < PK; p4 += 4) {
            float4 z4[4];
#pragma unroll
            for (int t = 0; t < 4; ++t) z4[t] = *(const float4*)&zbuf[t][p4];
#pragma unroll
            for (int pp = 0; pp < 4; ++pp) {
                float4 w4 = ld4<ISBF>(Wm, (size_t)(p4 + pp) * DM + e0);
#pragma unroll
                for (int t = 0; t < 4; ++t) {
                    float zp = f4c(z4[t], pp);
                    accm[t][0] += zp * w4.x; accm[t][1] += zp * w4.y;
                    accm[t][2] += zp * w4.z; accm[t][3] += zp * w4.w;
                }
            }
        }
        float4 bm4 = ld4<ISBF>(bm, e0);
#pragma unroll
        for (int t = 0; t < 4; ++t) {
            const size_t tok = (size_t)blockIdx.x * 4 + t;
            st4<ISBF>(out, tok * DM + e0,
                      make_float4(accm[t][0]+bm4.x, accm[t][1]+bm4.y,
                                  accm[t][2]+bm4.z, accm[t][3]+bm4.w));
        }
    }
}

extern "C" void kernel_launch(void* const* d_in, const int* in_sizes, int n_in,
                              void* d_out, int out_size, void* d_ws, size_t ws_size,
                              hipStream_t stream) {
    const void* x   = d_in[0];
    const void* sg  = d_in[1];
    const void* sb  = d_in[2];
    const void* pg  = d_in[3];
    const void* pb  = d_in[4];
    const void* w1  = d_in[5];
    const void* b1  = d_in[6];
    const void* w2  = d_in[7];
    const void* b2  = d_in[8];
    const void* pkg = d_in[9];
    const void* pkb = d_in[10];
    const void* Wm  = d_in[11];
    const void* bm  = d_in[12];

    int* flag = (int*)d_ws;
    u16* base = (u16*)((char*)d_ws + 16);
    u16* w1p = base;                       // 98304 el
    u16* w2p = base + 98304;               // 98304 el
    u16* wmt = base + 196608;              // 1048576 el
    u16* zws = base + 196608 + 1048576;    // 16777216 el
    float* gws = (float*)(base + 18022400);          // 1024 f32
    const size_t ws_needed = 16 + (size_t)18022400 * sizeof(u16) + PK * sizeof(float);

    detect_dtype<<<1, 256, 0, stream>>>(x, flag);

    if (ws_size >= ws_needed) {
        prep_mfma<true ><<<640, 256, 0, stream>>>(w1, w2, Wm, sg, w1p, w2p, wmt, gws, flag);
        prep_mfma<false><<<640, 256, 0, stream>>>(w1, w2, Wm, sg, w1p, w2p, wmt, gws, flag);
        conv_fused<true ><<<NTOK / 8, 256, 0, stream>>>(x, sb, pg, pb, b1, b2, pkg, pkb, w1p, w2p, gws, zws, flag);
        conv_fused<false><<<NTOK / 8, 256, 0, stream>>>(x, sb, pg, pb, b1, b2, pkg, pkb, w1p, w2p, gws, zws, flag);
        gemm_out<true ><<<(NTOK / 128) * (DM / 128), 256, 0, stream>>>(zws, wmt, bm, d_out, flag);
        gemm_out<false><<<(NTOK / 128) * (DM / 128), 256, 0, stream>>>(zws, wmt, bm, d_out, flag);
    } else {
        slotconv_scalar<true ><<<NTOK / 4, 256, 0, stream>>>(
            x, sg, sb, pg, pb, w1, b1, w2, b2, pkg, pkb, Wm, bm, d_out, flag);
        slotconv_scalar<false><<<NTOK / 4, 256, 0, stream>>>(
            x, sg, sb, pg, pb, w1, b1, w2, b2, pkg, pkb, Wm, bm, d_out, flag);
    }
}